// Round 6
// baseline (284.695 us; speedup 1.0000x reference)
//
#include <hip/hip_runtime.h>
#include <math.h>

// Problem constants (reference: B=2, S=2048, D=1024, H=16, HD=64)
#define B_ 2
#define S_ 2048
#define D_ 1024
#define H_ 16
#define HD_ 64

typedef unsigned short ushort8 __attribute__((ext_vector_type(8)));
typedef unsigned int u32x4 __attribute__((ext_vector_type(4)));
typedef __bf16 bf16x8 __attribute__((ext_vector_type(8)));
typedef __bf16 bf16x2 __attribute__((ext_vector_type(2)));
typedef float f32x4 __attribute__((ext_vector_type(4)));

__device__ __forceinline__ unsigned short f2bf(float f) {
    union { __bf16 b; unsigned short u; } v;
    v.b = (__bf16)f;                       // native v_cvt, RNE
    return v.u;
}
__device__ __forceinline__ float bf2f(unsigned short u) {
    union { unsigned short u; __bf16 b; } v; v.u = u;
    return (float)v.b;
}
__device__ __forceinline__ void split2x4(f32x4 a, f32x4 b, ushort8& hi, ushort8& lo) {
    #pragma unroll
    for (int i = 0; i < 4; ++i) {
        unsigned short h = f2bf(a[i]); hi[i] = h; lo[i] = f2bf(a[i] - bf2f(h));
    }
    #pragma unroll
    for (int i = 0; i < 4; ++i) {
        unsigned short h = f2bf(b[i]); hi[4 + i] = h; lo[4 + i] = f2bf(b[i] - bf2f(h));
    }
}

// XOR swizzle for [R][64] bf16 tiles (128B rows): in-row 16B-chunk permute by row&7.
#define SWZ(row, col) ((((row)) << 6) + (((col)) ^ ((((row)) & 7) << 3)))

__device__ __forceinline__ f32x4 mfma_bf16(bf16x8 a, bf16x8 b, f32x4 c) {
    return __builtin_amdgcn_mfma_f32_16x16x32_bf16(a, b, c, 0, 0, 0);
}

typedef __attribute__((address_space(1))) const void gvoid_t;
typedef __attribute__((address_space(3))) void lvoid_t;
typedef __attribute__((address_space(3))) unsigned short lds_us_t;
__device__ __forceinline__ void gload_lds16(const void* g, void* l) {
    __builtin_amdgcn_global_load_lds((gvoid_t*)g, (lvoid_t*)l, 16, 0, 0);
}
// inline-asm LDS read: opaque to the compiler's waitcnt pass (counted vmcnt survives)
__device__ __forceinline__ bf16x8 dsr128(unsigned addr) {
    u32x4 r;
    asm volatile("ds_read_b128 %0, %1" : "=v"(r) : "v"(addr));
    union { u32x4 u; bf16x8 b; } cv; cv.u = r; return cv.b;
}

// ---------------------------------------------------------------------------
// conv_rows: fp32 [4096][1024] -> hi/lo bf16, pre-swizzled chunks (key = row&7)
// ---------------------------------------------------------------------------
__global__ __launch_bounds__(256) void conv_rows_kernel(
    const float* __restrict__ in, unsigned short* __restrict__ ohi,
    unsigned short* __restrict__ olo)
{
    const int id = blockIdx.x * 256 + threadIdx.x;   // [0, 4096*128)
    const int r = id >> 7, c = id & 127;
    const float* s = in + (size_t)r * 1024 + c * 8;
    f32x4 v0 = *(const f32x4*)s, v1 = *(const f32x4*)(s + 4);
    ushort8 hi, lo;
    split2x4(v0, v1, hi, lo);
    const int oc = (c & ~7) | ((c ^ r) & 7);
    *(ushort8*)&ohi[(size_t)r * 1024 + oc * 8] = hi;
    *(ushort8*)&olo[(size_t)r * 1024 + oc * 8] = lo;
}

// ---------------------------------------------------------------------------
// conv_wt: W fp32 [1024 k][ldw] -> Wt hi/lo bf16 [N][1024], transposed +
// pre-swizzled (key = n&7). Grid (K/64, N/64).
// ---------------------------------------------------------------------------
__global__ __launch_bounds__(256) void conv_wt_kernel(
    const float* __restrict__ W, int ldw,
    unsigned short* __restrict__ othi, unsigned short* __restrict__ otlo)
{
    __shared__ float T[64][65];
    const int tid = threadIdx.x;
    const int kx = blockIdx.x * 64, ny = blockIdx.y * 64;
    const int kl = tid >> 2, c0 = (tid & 3) * 16;
    const float* s = W + (size_t)(kx + kl) * ldw + ny + c0;
    #pragma unroll
    for (int i = 0; i < 4; ++i) *(f32x4*)&T[kl][c0 + 4 * i] = *(const f32x4*)(s + 4 * i);
    __syncthreads();
    const int nl = tid >> 2, jj = (tid & 3) * 2;
    #pragma unroll
    for (int p = 0; p < 2; ++p) {
        const int j = jj + p;
        f32x4 a, b;
        #pragma unroll
        for (int i = 0; i < 4; ++i) a[i] = T[j * 8 + i][nl];
        #pragma unroll
        for (int i = 0; i < 4; ++i) b[i] = T[j * 8 + 4 + i][nl];
        ushort8 hi, lo;
        split2x4(a, b, hi, lo);
        const int row = ny + nl;
        const int chunk = blockIdx.x * 8 + (j ^ (nl & 7));
        *(ushort8*)&othi[(size_t)row * 1024 + chunk * 8] = hi;
        *(ushort8*)&otlo[(size_t)row * 1024 + chunk * 8] = lo;
    }
}

// ---------------------------------------------------------------------------
// Split-bf16 MFMA GEMM, counted-vmcnt pipelined (T3/T4/T5).
// 128x128 tile, BK=64, 512 thr / 8 waves (each 64m x 32n), 2-tile LDS dbuf
// (128 KB). Raw s_barrier + manual vmcnt(8): staging loads stay in flight
// across barriers; asm ds_read keeps the compiler from inserting vmcnt(0).
// A, Bt hi/lo bf16, globally pre-swizzled. OUTMODE 0: fp32 C. 1: hi/lo bf16.
// ---------------------------------------------------------------------------
template<int OUTMODE>
__global__ __launch_bounds__(512, 1) void gemm8_kernel(
    const unsigned short* __restrict__ Ahi, const unsigned short* __restrict__ Alo,
    const unsigned short* __restrict__ Bthi, const unsigned short* __restrict__ Btlo,
    const float* __restrict__ bias, float* __restrict__ Cf,
    unsigned short* __restrict__ Ohi, unsigned short* __restrict__ Olo,
    int M, int N, int K)
{
    // per tile-buffer (65536 B): region (arr*2+half)*8192 B, arr: Ahi,Alo,Bhi,Blo
    // each region = [64 rows][64 elems] bf16 (swizzled content from global).
    __shared__ __align__(16) unsigned short lds[65536];   // 128 KB total

    const int tid = threadIdx.x, lane = tid & 63, w = tid >> 6;   // 8 waves
    const int wm = w >> 2, wn = w & 3;                            // 2m x 4n
    const int m0 = blockIdx.y * 128, n0 = blockIdx.x * 128;
    const int col = lane & 15, oct = ((lane >> 4) & 3) * 8, g = lane >> 4;
    const int NT = K >> 6;

    // ---- staging: half-tile ht of K-tile tt -> buffer tt&1 (8 gloads/thread/tile)
    auto stage = [&](int tt, int ht) {
        const unsigned bufb = (tt & 1) ? 65536u : 0u;
        const int kt = tt * 64;
        #pragma unroll
        for (int j = 0; j < 4; ++j) {
            const int bb = w * 4 + j;            // 0..31
            const int sel = bb >> 3;             // Ahi,Alo,Bhi,Blo
            const int g8 = bb & 7;
            const int rin = ht * 64 + g8 * 8 + (lane >> 3);
            const unsigned short* src = (sel == 0) ? Ahi : (sel == 1) ? Alo
                                      : (sel == 2) ? Bthi : Btlo;
            const size_t rowg = (sel < 2) ? (size_t)(m0 + rin) : (size_t)(n0 + rin);
            gload_lds16(src + rowg * K + kt + (lane & 7) * 8,
                        (void*)((char*)lds + bufb + (sel * 2 + ht) * 8192 + g8 * 1024));
        }
    };

    // ---- per-lane ds_read base addresses (byte, within-buffer) ----
    const unsigned ldsb = (unsigned)(size_t)(lds_us_t*)lds;
    const int hb = wn >> 1;
    const int sw = (col & 7) << 3;
    const unsigned sk0 = (unsigned)(oct ^ sw);
    const unsigned sk1 = (unsigned)((32 + oct) ^ sw);
    const unsigned aB[2] = { ldsb + 2u * ((unsigned)wm * 4096u + (unsigned)col * 64u + sk0),
                             ldsb + 2u * ((unsigned)wm * 4096u + (unsigned)col * 64u + sk1) };
    const unsigned bB[2] = { ldsb + 2u * ((4u + hb) * 4096u + ((unsigned)((wn & 1) * 32 + col)) * 64u + sk0),
                             ldsb + 2u * ((4u + hb) * 4096u + ((unsigned)((wn & 1) * 32 + col)) * 64u + sk1) };

    f32x4 acc[4][2] = {};

    // ---- prologue: stage tiles 0 and 1 (16 loads in flight) ----
    stage(0, 0); stage(0, 1); stage(1, 0); stage(1, 1);

    for (int tt = 0; tt < NT; ++tt) {
        if (tt + 1 < NT) asm volatile("s_waitcnt vmcnt(8)" ::: "memory");
        else             asm volatile("s_waitcnt vmcnt(0)" ::: "memory");
        __builtin_amdgcn_s_barrier();           // (X) buf tt&1 published
        const unsigned bo = (tt & 1) ? 65536u : 0u;

        bf16x8 ah[2][4], al[2][4], bh[2][2], bl[2][2];
        #pragma unroll
        for (int kh = 0; kh < 2; ++kh) {
            #pragma unroll
            for (int mi = 0; mi < 4; ++mi) {
                ah[kh][mi] = dsr128(aB[kh] + bo + mi * 2048u);
                al[kh][mi] = dsr128(aB[kh] + bo + mi * 2048u + 16384u);
            }
            #pragma unroll
            for (int nj = 0; nj < 2; ++nj) {
                bh[kh][nj] = dsr128(bB[kh] + bo + nj * 2048u);
                bl[kh][nj] = dsr128(bB[kh] + bo + nj * 2048u + 16384u);
            }
        }
        asm volatile("s_waitcnt lgkmcnt(0)" ::: "memory");
        __builtin_amdgcn_sched_barrier(0);      // rule #18: pin MFMA after the wait

        __builtin_amdgcn_s_setprio(1);
        #pragma unroll
        for (int kh = 0; kh < 2; ++kh)
            #pragma unroll
            for (int mi = 0; mi < 4; ++mi)
                #pragma unroll
                for (int nj = 0; nj < 2; ++nj) {
                    acc[mi][nj] = mfma_bf16(ah[kh][mi], bh[kh][nj], acc[mi][nj]);
                    acc[mi][nj] = mfma_bf16(ah[kh][mi], bl[kh][nj], acc[mi][nj]);
                    acc[mi][nj] = mfma_bf16(al[kh][mi], bh[kh][nj], acc[mi][nj]);
                }
        __builtin_amdgcn_s_setprio(0);

        __builtin_amdgcn_s_barrier();           // (Y) all reads of buf tt&1 done
        if (tt + 2 < NT) { stage(tt + 2, 0); stage(tt + 2, 1); }
    }

    // ---- epilogue: per-wave LDS transpose (stride 36 breaks conflicts) ----
    __syncthreads();
    float* ow = (float*)((char*)lds + w * 9216);   // [64][36] fp32 per wave
    #pragma unroll
    for (int mi = 0; mi < 4; ++mi)
        #pragma unroll
        for (int nj = 0; nj < 2; ++nj)
            #pragma unroll
            for (int r = 0; r < 4; ++r)
                ow[(mi * 16 + g * 4 + r) * 36 + nj * 16 + col] = acc[mi][nj][r];
    __builtin_amdgcn_wave_barrier();

    if (OUTMODE == 0) {
        const int c4 = lane & 7;
        const int nabs = n0 + wn * 32 + c4 * 4;
        f32x4 bi = *(const f32x4*)&bias[nabs];
        #pragma unroll
        for (int it = 0; it < 8; ++it) {
            const int row = it * 8 + (lane >> 3);
            f32x4 v = *(const f32x4*)&ow[row * 36 + c4 * 4];
            v += bi;
            *(f32x4*)&Cf[(size_t)(m0 + wm * 64 + row) * N + nabs] = v;
        }
    } else {
        const int cg = lane & 3;
        const int nabs = n0 + wn * 32 + cg * 8;
        f32x4 bi0 = *(const f32x4*)&bias[nabs];
        f32x4 bi1 = *(const f32x4*)&bias[nabs + 4];
        #pragma unroll
        for (int it = 0; it < 4; ++it) {
            const int row = it * 16 + (lane >> 2);
            f32x4 v0 = *(const f32x4*)&ow[row * 36 + cg * 8];
            f32x4 v1 = *(const f32x4*)&ow[row * 36 + cg * 8 + 4];
            v0 += bi0; v1 += bi1;
            const int m = m0 + wm * 64 + row;
            ushort8 hi, lo;
            split2x4(v0, v1, hi, lo);
            const int c = (n0 >> 3) + wn * 4 + cg;
            const int phys = (c & ~7) | ((c ^ m) & 7);
            const size_t off = (size_t)m * N + (size_t)phys * 8;
            *(ushort8*)&Ohi[off] = hi;
            *(ushort8*)&Olo[off] = lo;
        }
    }
}

// ---------------------------------------------------------------------------
// V suffix tile sums (vectorized): tsum[h][t][d] = sum_{k in tile t} V[k][d]
// ---------------------------------------------------------------------------
__global__ __launch_bounds__(256) void vsuf_part_kernel(
    const unsigned short* __restrict__ qh, const unsigned short* __restrict__ ql,
    float* __restrict__ tsum)
{
    const int h = blockIdx.x, tg = blockIdx.y;    // grid (16, 8)
    const int tl = threadIdx.x >> 6, lane = threadIdx.x & 63;
    const int t = tg * 4 + tl;
    const int dgrp = lane & 7, rr = lane >> 3;
    const int colbase = h * 192 + 128;
    float sacc[8] = {};
    for (int kk = 0; kk < 8; ++kk) {
        const int row = t * 64 + rr + kk * 8;
        const size_t off = (size_t)row * 3072 + colbase + ((dgrp ^ rr) << 3);
        ushort8 vh = *(const ushort8*)&qh[off];
        ushort8 vl = *(const ushort8*)&ql[off];
        #pragma unroll
        for (int e = 0; e < 8; ++e) sacc[e] += bf2f(vh[e]) + bf2f(vl[e]);
    }
    #pragma unroll
    for (int off = 8; off < 64; off <<= 1)
        #pragma unroll
        for (int e = 0; e < 8; ++e) sacc[e] += __shfl_xor(sacc[e], off);
    if (rr == 0) {
        float* dst = &tsum[((size_t)h * 32 + t) * 64 + dgrp * 8];
        f32x4 v0, v1;
        #pragma unroll
        for (int e = 0; e < 4; ++e) { v0[e] = sacc[e]; v1[e] = sacc[4 + e]; }
        *(f32x4*)dst = v0;
        *(f32x4*)(dst + 4) = v1;
    }
}

__global__ __launch_bounds__(64) void vsuf_scan_kernel(
    const float* __restrict__ tsum, float* __restrict__ vsuf)
{
    const int h = blockIdx.x, d = threadIdx.x;    // 16 blocks x 64 thr
    float acc = 0.f;
    vsuf[((size_t)h * 33 + 32) * 64 + d] = 0.f;
    for (int t = 31; t >= 0; --t) {
        acc += tsum[((size_t)h * 32 + t) * 64 + d];
        vsuf[((size_t)h * 33 + t) * 64 + d] = acc;
    }
}

// ---------------------------------------------------------------------------
// Causal-skip MFMA flash attention with key-range segmentation. (r4/r5 proven)
// ---------------------------------------------------------------------------
__global__ __launch_bounds__(256, 4) void attn_kernel(
    const unsigned short* __restrict__ qh, const unsigned short* __restrict__ ql,
    const float* __restrict__ vsuf,
    unsigned short* __restrict__ ohi, unsigned short* __restrict__ olo,
    float* __restrict__ partO, float* __restrict__ partML,
    int brow)
{
    __shared__ __align__(16) unsigned short lds[16384];   // 32 KB

    const int tid = threadIdx.x, lane = tid & 63, w = tid >> 6;
    const int g = lane >> 4, oct = g * 8, col = lane & 15;
    const int h = blockIdx.y;
    const int kp = tid & 31, dg = tid >> 5;

    const int job = blockIdx.x;
    int i = job, s = 0, slot = -1;
    if (job >= 10) {
        int r = job - 10, cum = 0;
        for (int ii = 10; ii < 32; ++ii) {
            const int ns = (ii + 10) / 10;
            if (r < cum + ns) { i = ii; s = r - cum; break; }
            cum += ns;
        }
        slot = (size_t)0 + h * 58 + (job - 10);
    }
    const int q0 = i * 64;
    const int ntile_all = i + 1;
    const int t_begin = s * 10;
    const int t_end = (slot < 0) ? ntile_all : min(t_begin + 10, ntile_all);
    const bool isseg = (slot >= 0);

    auto kissue = [&](int ktbase, ushort8* kr) {
        #pragma unroll
        for (int j = 0; j < 4; ++j) {
            const int cc = w * 4 + j;
            const unsigned short* src = (cc < 8) ? qh : ql;
            const int row = ktbase + (cc & 7) * 8 + (lane >> 3);
            kr[j] = *(const ushort8*)(src + (size_t)row * 3072 + h * 192 + 64 + (lane & 7) * 8);
        }
    };
    auto kwrite = [&](const ushort8* kr) {
        #pragma unroll
        for (int j = 0; j < 4; ++j) {
            const int cc = w * 4 + j;
            *(ushort8*)&lds[(cc < 8 ? 0 : 4096) + (cc & 7) * 512 + lane * 8] = kr[j];
        }
    };
    auto vload = [&](int ktbase, bf16x8& vA, bf16x8& vB) {
        const int r0 = ktbase + 2 * kp, r1 = r0 + 1;
        const int pA = dg ^ (r0 & 7), pB = dg ^ (r1 & 7);
        vA = *(const bf16x8*)&qh[(size_t)r0 * 3072 + h * 192 + 128 + pA * 8];
        vB = *(const bf16x8*)&qh[(size_t)r1 * 3072 + h * 192 + 128 + pB * 8];
    };
    auto vwrite = [&](bf16x8 vA, bf16x8 vB) {
        #pragma unroll
        for (int e = 0; e < 8; ++e) {
            const int d = dg * 8 + e;
            bf16x2 pr; pr[0] = vA[e]; pr[1] = vB[e];
            *(bf16x2*)&lds[8192 + SWZ(d, 2 * kp)] = pr;
        }
    };

    #pragma unroll
    for (int j = 0; j < 4; ++j) {
        const int cc = w * 4 + j;
        const unsigned short* src = (cc < 8) ? qh : ql;
        const int c7 = cc & 7;
        const int row = q0 + c7 * 8 + (lane >> 3);
        gload_lds16(src + (size_t)row * 3072 + h * 192 + (lane & 7) * 8,
                    &lds[(cc < 8 ? 0 : 4096) + c7 * 512]);
    }
    ushort8 kr[4]; bf16x8 vA, vB;
    kissue(t_begin * 64, kr);
    vload(t_begin * 64, vA, vB);
    __syncthreads();
    bf16x8 qfh[2], qfl[2];
    {
        const int qrow = w * 16 + col;
        qfh[0] = *(const bf16x8*)&lds[SWZ(qrow, oct)];
        qfh[1] = *(const bf16x8*)&lds[SWZ(qrow, 32 + oct)];
        qfl[0] = *(const bf16x8*)&lds[4096 + SWZ(qrow, oct)];
        qfl[1] = *(const bf16x8*)&lds[4096 + SWZ(qrow, 32 + oct)];
    }
    __syncthreads();
    kwrite(kr);
    vwrite(vA, vB);
    __syncthreads();

    const int qg = q0 + w * 16 + col;
    float m_run = isseg ? -INFINITY : 0.f;
    float l_run = 0.f;
    f32x4 oacc[4] = {};

    for (int t = t_begin; t < t_end; ++t) {
        const int kt = t * 64;
        const bool pf = (t + 1 < t_end);
        if (pf) { kissue(kt + 64, kr); vload(kt + 64, vA, vB); }

        f32x4 sacc[4] = {};
        #pragma unroll
        for (int c = 0; c < 2; ++c)
            #pragma unroll
            for (int t4 = 0; t4 < 4; ++t4) {
                const int krow = t4 * 16 + col;
                bf16x8 kh = *(const bf16x8*)&lds[SWZ(krow, c * 32 + oct)];
                bf16x8 kl = *(const bf16x8*)&lds[4096 + SWZ(krow, c * 32 + oct)];
                sacc[t4] = mfma_bf16(kh, qfh[c], sacc[t4]);
                sacc[t4] = mfma_bf16(kh, qfl[c], sacc[t4]);
                sacc[t4] = mfma_bf16(kl, qfh[c], sacc[t4]);
            }

        float p[16];
        float mx = -INFINITY;
        if (t == ntile_all - 1) {
            #pragma unroll
            for (int t4 = 0; t4 < 4; ++t4)
                #pragma unroll
                for (int r = 0; r < 4; ++r) {
                    float sv = sacc[t4][r] * 0.125f;
                    if (kt + t4 * 16 + g * 4 + r > qg) sv = 0.0f;
                    p[t4 * 4 + r] = sv; mx = fmaxf(mx, sv);
                }
        } else {
            #pragma unroll
            for (int t4 = 0; t4 < 4; ++t4)
                #pragma unroll
                for (int r = 0; r < 4; ++r) {
                    float sv = sacc[t4][r] * 0.125f;
                    p[t4 * 4 + r] = sv; mx = fmaxf(mx, sv);
                }
        }
        mx = fmaxf(mx, __shfl_xor(mx, 16));
        mx = fmaxf(mx, __shfl_xor(mx, 32));
        const float mnew = fmaxf(m_run, mx);
        const float corr = __expf(m_run - mnew);
        float ls = 0.f;
        unsigned short* Pw = &lds[12288 + w * 1024];
        #pragma unroll
        for (int t4 = 0; t4 < 4; ++t4)
            #pragma unroll
            for (int rp = 0; rp < 2; ++rp) {
                float e0 = __expf(p[t4 * 4 + rp * 2] - mnew);
                float e1 = __expf(p[t4 * 4 + rp * 2 + 1] - mnew);
                ls += e0 + e1;
                bf16x2 pk; pk[0] = (__bf16)e0; pk[1] = (__bf16)e1;
                *(bf16x2*)&Pw[SWZ(col, t4 * 16 + g * 4 + rp * 2)] = pk;
            }
        ls += __shfl_xor(ls, 16);
        ls += __shfl_xor(ls, 32);
        l_run = l_run * corr + ls;
        m_run = mnew;

        __builtin_amdgcn_wave_barrier();

        __syncthreads();                 // (A)
        if (pf) kwrite(kr);

        #pragma unroll
        for (int dt = 0; dt < 4; ++dt) {
            oacc[dt][0] *= corr; oacc[dt][1] *= corr;
            oacc[dt][2] *= corr; oacc[dt][3] *= corr;
        }
        #pragma unroll
        for (int c = 0; c < 2; ++c) {
            bf16x8 pfv = *(const bf16x8*)&Pw[SWZ(col, c * 32 + oct)];
            #pragma unroll
            for (int dt = 0; dt < 4; ++dt) {
                bf16x8 vh = *(const bf16x8*)&lds[8192 + SWZ(dt * 16 + col, c * 32 + oct)];
                oacc[dt] = mfma_bf16(vh, pfv, oacc[dt]);
            }
        }

        __syncthreads();                 // (B)
        if (pf) vwrite(vA, vB);
    }

    if (isseg) {
        float* po = partO + (size_t)slot * 4096;
        #pragma unroll
        for (int dt = 0; dt < 4; ++dt)
            #pragma unroll
            for (int r = 0; r < 4; ++r)
                po[(dt * 16 + g * 4 + r) * 64 + w * 16 + col] = oacc[dt][r];
        if (g == 0) {
            partML[(size_t)slot * 128 + w * 16 + col] = m_run;
            partML[(size_t)slot * 128 + 64 + w * 16 + col] = l_run;
        }
        return;
    }

    {
        const float wt = __expf(-m_run);
        l_run += (float)(S_ - q0 - 64) * wt;
        const float* vs = vsuf + ((size_t)h * 33 + (i + 1)) * 64;
        #pragma unroll
        for (int dt = 0; dt < 4; ++dt)
            #pragma unroll
            for (int r = 0; r < 4; ++r)
                oacc[dt][r] += wt * vs[dt * 16 + g * 4 + r];
    }
    const float inv = 1.f / l_run;
    float* ow = (float*)&lds[w * 4096];
    const int q = lane >> 2, jj = lane & 3;
    #pragma unroll
    for (int half = 0; half < 2; ++half) {
        __builtin_amdgcn_wave_barrier();
        #pragma unroll
        for (int t4 = 0; t4 < 2; ++t4)
            #pragma unroll
            for (int r = 0; r < 4; ++r)
                ow[col * 40 + t4 * 16 + g * 4 + r] = oacc[half * 2 + t4][r] * inv;
        __builtin_amdgcn_wave_barrier();
        f32x4 v0 = *(const f32x4*)&ow[q * 40 + jj * 8];
        f32x4 v1 = *(const f32x4*)&ow[q * 40 + jj * 8 + 4];
        ushort8 hi, lo;
        split2x4(v0, v1, hi, lo);
        const int m = brow + q0 + w * 16 + q;
        const int chunk = (half * 4 + jj) ^ (m & 7);
        const size_t off = (size_t)m * 1024 + h * 64 + chunk * 8;
        *(ushort8*)&ohi[off] = hi;
        *(ushort8*)&olo[off] = lo;
    }
}

// ---------------------------------------------------------------------------
// Combine partials for split q-tiles (i>=10). (r4/r5 proven)
// ---------------------------------------------------------------------------
__global__ __launch_bounds__(256) void attn_combine_kernel(
    const float* __restrict__ partO, const float* __restrict__ partML,
    const float* __restrict__ vsuf,
    unsigned short* __restrict__ ohi, unsigned short* __restrict__ olo,
    int brow)
{
    const int i = 10 + blockIdx.x;
    const int h = blockIdx.y;
    const int nseg = (i + 10) / 10;
    int cum = 0;
    for (int j = 10; j < i; ++j) cum += (j + 10) / 10;
    const int slot0 = h * 58 + cum;
    const int q = threadIdx.x & 63, dgrp = threadIdx.x >> 6;
    const int q0 = i * 64;

    float mstar = 0.f;
    for (int sg = 0; sg < nseg; ++sg)
        mstar = fmaxf(mstar, partML[(size_t)(slot0 + sg) * 128 + q]);
    const float wtail = __expf(-mstar);
    float lstar = (float)(S_ - q0 - 64) * wtail;

    float od[16];
    const float* vs = vsuf + ((size_t)h * 33 + i + 1) * 64 + dgrp * 16;
    #pragma unroll
    for (int k = 0; k < 16; ++k) od[k] = wtail * vs[k];

    for (int sg = 0; sg < nseg; ++sg) {
        const float ms = partML[(size_t)(slot0 + sg) * 128 + q];
        const float lsv = partML[(size_t)(slot0 + sg) * 128 + 64 + q];
        const float wv = __expf(ms - mstar);
        lstar += lsv * wv;
        const float* po = partO + (size_t)(slot0 + sg) * 4096 + (size_t)(dgrp * 16) * 64 + q;
        #pragma unroll
        for (int k = 0; k < 16; ++k) od[k] += wv * po[k * 64];
    }

    const float inv = 1.f / lstar;
    f32x4 a0, a1, b0, b1;
    #pragma unroll
    for (int k = 0; k < 4; ++k) {
        a0[k] = od[k] * inv; a1[k] = od[4 + k] * inv;
        b0[k] = od[8 + k] * inv; b1[k] = od[12 + k] * inv;
    }
    ushort8 hi0, lo0, hi1, lo1;
    split2x4(a0, a1, hi0, lo0);
    split2x4(b0, b1, hi1, lo1);
    const int mrow = brow + q0 + q;
    const int c0 = (dgrp * 2) ^ (mrow & 7);
    const int c1 = (dgrp * 2 + 1) ^ (mrow & 7);
    const size_t base = (size_t)mrow * 1024 + h * 64;
    *(ushort8*)&ohi[base + c0 * 8] = hi0;
    *(ushort8*)&olo[base + c0 * 8] = lo0;
    *(ushort8*)&ohi[base + c1 * 8] = hi1;
    *(ushort8*)&olo[base + c1 * 8] = lo1;
}

// ---------------------------------------------------------------------------
extern "C" void kernel_launch(void* const* d_in, const int* in_sizes, int n_in,
                              void* d_out, int out_size, void* d_ws, size_t ws_size,
                              hipStream_t stream) {
    const float* x     = (const float*)d_in[0];   // [B,S,D]
    const float* W_qkv = (const float*)d_in[1];   // [D,3D]
    const float* b_qkv = (const float*)d_in[2];   // [3D]
    const float* W_out = (const float*)d_in[3];   // [D,D]
    const float* b_out = (const float*)d_in[4];   // [D]
    float* out = (float*)d_out;                   // [B,S,D]

    unsigned short* us  = (unsigned short*)d_ws;
    unsigned short* Wqh = us;                                  // [3072][1024]
    unsigned short* Wql = Wqh + (size_t)3072 * 1024;
    unsigned short* Woh = Wql + (size_t)3072 * 1024;           // [1024][1024]
    unsigned short* Wol = Woh + (size_t)1024 * 1024;
    unsigned short* XAhi = Wol + (size_t)1024 * 1024;          // [4096][1024] X, then attn-out
    unsigned short* XAlo = XAhi + (size_t)4096 * 1024;
    unsigned short* QKVh = XAlo + (size_t)4096 * 1024;         // [2048][3072] per batch
    unsigned short* QKVl = QKVh + (size_t)2048 * 3072;
    float* tsum = (float*)(QKVl + (size_t)2048 * 3072);        // [16][32][64]
    float* vsuf = tsum + (size_t)16 * 32 * 64;                 // [16][33][64]

    float* partO  = out;                                       // [928][4096]
    float* partML = out + (size_t)928 * 4096;                  // [928][128]

    conv_wt_kernel<<<dim3(16, 48), 256, 0, stream>>>(W_qkv, 3072, Wqh, Wql);
    conv_wt_kernel<<<dim3(16, 16), 256, 0, stream>>>(W_out, 1024, Woh, Wol);
    conv_rows_kernel<<<dim3(2048), 256, 0, stream>>>(x, XAhi, XAlo);

    for (int b = 0; b < 2; ++b) {
        gemm8_kernel<1><<<dim3(24, 16), 512, 0, stream>>>(
            XAhi + (size_t)b * 2048 * 1024, XAlo + (size_t)b * 2048 * 1024,
            Wqh, Wql, b_qkv, nullptr, QKVh, QKVl, 2048, 3072, 1024);
        vsuf_part_kernel<<<dim3(16, 8), 256, 0, stream>>>(QKVh, QKVl, tsum);
        vsuf_scan_kernel<<<dim3(16), 64, 0, stream>>>(tsum, vsuf);
        attn_kernel<<<dim3(68, 16), 256, 0, stream>>>(
            QKVh, QKVl, vsuf, XAhi, XAlo, partO, partML, b * 2048);
        attn_combine_kernel<<<dim3(22, 16), 256, 0, stream>>>(
            partO, partML, vsuf, XAhi, XAlo, b * 2048);
    }

    gemm8_kernel<0><<<dim3(8, 32), 512, 0, stream>>>(
        XAhi, XAlo, Woh, Wol, b_out, out, nullptr, nullptr, 4096, 1024, 1024);
}

// Round 8
// 236.321 us; speedup vs baseline: 1.2047x; 1.2047x over previous
//
#include <hip/hip_runtime.h>
#include <math.h>

// Problem constants (reference: B=2, S=2048, D=1024, H=16, HD=64)
#define B_ 2
#define S_ 2048
#define D_ 1024
#define H_ 16
#define HD_ 64

typedef unsigned short ushort8 __attribute__((ext_vector_type(8)));
typedef unsigned int u32x4 __attribute__((ext_vector_type(4)));
typedef __bf16 bf16x8 __attribute__((ext_vector_type(8)));
typedef __bf16 bf16x2 __attribute__((ext_vector_type(2)));
typedef float f32x4 __attribute__((ext_vector_type(4)));

__device__ __forceinline__ unsigned short f2bf(float f) {
    union { __bf16 b; unsigned short u; } v;
    v.b = (__bf16)f;                       // native v_cvt, RNE
    return v.u;
}
__device__ __forceinline__ float bf2f(unsigned short u) {
    union { unsigned short u; __bf16 b; } v; v.u = u;
    return (float)v.b;
}
__device__ __forceinline__ void split2x4(f32x4 a, f32x4 b, ushort8& hi, ushort8& lo) {
    #pragma unroll
    for (int i = 0; i < 4; ++i) {
        unsigned short h = f2bf(a[i]); hi[i] = h; lo[i] = f2bf(a[i] - bf2f(h));
    }
    #pragma unroll
    for (int i = 0; i < 4; ++i) {
        unsigned short h = f2bf(b[i]); hi[4 + i] = h; lo[4 + i] = f2bf(b[i] - bf2f(h));
    }
}

// XOR swizzle for [R][64] bf16 tiles (128B rows): in-row 16B-chunk permute by row&7.
#define SWZ(row, col) ((((row)) << 6) + (((col)) ^ ((((row)) & 7) << 3)))

__device__ __forceinline__ f32x4 mfma_bf16(bf16x8 a, bf16x8 b, f32x4 c) {
    return __builtin_amdgcn_mfma_f32_16x16x32_bf16(a, b, c, 0, 0, 0);
}

typedef __attribute__((address_space(1))) const void gvoid_t;
typedef __attribute__((address_space(3))) void lvoid_t;
typedef __attribute__((address_space(3))) unsigned short lds_us_t;
__device__ __forceinline__ void gload_lds16(const void* g, void* l) {
    __builtin_amdgcn_global_load_lds((gvoid_t*)g, (lvoid_t*)l, 16, 0, 0);
}
// inline-asm LDS read: opaque to the compiler's waitcnt pass (counted vmcnt survives)
__device__ __forceinline__ bf16x8 dsr128(unsigned addr) {
    u32x4 r;
    asm volatile("ds_read_b128 %0, %1" : "=v"(r) : "v"(addr));
    union { u32x4 u; bf16x8 b; } cv; cv.u = r; return cv.b;
}

// ---------------------------------------------------------------------------
// conv_rows: fp32 [4096][1024] -> hi/lo bf16, pre-swizzled chunks (key = row&7)
// ---------------------------------------------------------------------------
__global__ __launch_bounds__(256) void conv_rows_kernel(
    const float* __restrict__ in, unsigned short* __restrict__ ohi,
    unsigned short* __restrict__ olo)
{
    const int id = blockIdx.x * 256 + threadIdx.x;   // [0, 4096*128)
    const int r = id >> 7, c = id & 127;
    const float* s = in + (size_t)r * 1024 + c * 8;
    f32x4 v0 = *(const f32x4*)s, v1 = *(const f32x4*)(s + 4);
    ushort8 hi, lo;
    split2x4(v0, v1, hi, lo);
    const int oc = (c & ~7) | ((c ^ r) & 7);
    *(ushort8*)&ohi[(size_t)r * 1024 + oc * 8] = hi;
    *(ushort8*)&olo[(size_t)r * 1024 + oc * 8] = lo;
}

// ---------------------------------------------------------------------------
// conv_wt: W fp32 [1024 k][ldw] -> Wt hi/lo bf16 [N][1024], transposed +
// pre-swizzled (key = n&7). Grid (K/64, N/64).
// ---------------------------------------------------------------------------
__global__ __launch_bounds__(256) void conv_wt_kernel(
    const float* __restrict__ W, int ldw,
    unsigned short* __restrict__ othi, unsigned short* __restrict__ otlo)
{
    __shared__ float T[64][65];
    const int tid = threadIdx.x;
    const int kx = blockIdx.x * 64, ny = blockIdx.y * 64;
    const int kl = tid >> 2, c0 = (tid & 3) * 16;
    const float* s = W + (size_t)(kx + kl) * ldw + ny + c0;
    #pragma unroll
    for (int i = 0; i < 4; ++i) *(f32x4*)&T[kl][c0 + 4 * i] = *(const f32x4*)(s + 4 * i);
    __syncthreads();
    const int nl = tid >> 2, jj = (tid & 3) * 2;
    #pragma unroll
    for (int p = 0; p < 2; ++p) {
        const int j = jj + p;
        f32x4 a, b;
        #pragma unroll
        for (int i = 0; i < 4; ++i) a[i] = T[j * 8 + i][nl];
        #pragma unroll
        for (int i = 0; i < 4; ++i) b[i] = T[j * 8 + 4 + i][nl];
        ushort8 hi, lo;
        split2x4(a, b, hi, lo);
        const int row = ny + nl;
        const int chunk = blockIdx.x * 8 + (j ^ (nl & 7));
        *(ushort8*)&othi[(size_t)row * 1024 + chunk * 8] = hi;
        *(ushort8*)&otlo[(size_t)row * 1024 + chunk * 8] = lo;
    }
}

// ---------------------------------------------------------------------------
// Split-bf16 MFMA GEMM, r5 geometry + counted-vmcnt double buffer.
// 128x128 tile, BK=64, 256 thr / 4 waves (each 64x64, 96 MFMA : 32 ds_read),
// 2 x 64KB LDS buffers. Loop: vmcnt(16) [tile t done, t+1 in flight] ->
// barrier -> 32 ds_read -> lgkmcnt(15) -> MFMA(kh0) -> lgkmcnt(0) ->
// MFMA(kh1) -> barrier -> stage(t+2). Never drains vmcnt to 0 mid-loop.
// XCD-aware bijective block swizzle (all grids % 8 == 0).
// A, Bt hi/lo bf16 globally pre-swizzled. OUTMODE 0: fp32 C. 1: hi/lo bf16.
// ---------------------------------------------------------------------------
template<int OUTMODE>
__global__ __launch_bounds__(256, 1) void gemm_pipe_kernel(
    const unsigned short* __restrict__ Ahi, const unsigned short* __restrict__ Alo,
    const unsigned short* __restrict__ Bthi, const unsigned short* __restrict__ Btlo,
    const float* __restrict__ bias, float* __restrict__ Cf,
    unsigned short* __restrict__ Ohi, unsigned short* __restrict__ Olo,
    int M, int N, int K)
{
    __shared__ __align__(16) unsigned short lds[65536];   // 2 x 64KB tile buffers

    const int tid = threadIdx.x, lane = tid & 63, w = tid >> 6;
    const int wm = w >> 1, wn = w & 1;
    // XCD-aware bijective swizzle (requires nwg % 8 == 0; true for all grids here)
    const int gx = gridDim.x, nwg = gx * gridDim.y;
    const int lin = blockIdx.y * gx + blockIdx.x;
    const int nl = (lin & 7) * (nwg >> 3) + (lin >> 3);
    const int m0 = (nl / gx) * 128, n0 = (nl % gx) * 128;
    const int col = lane & 15, oct = (lane >> 4) * 8, g = lane >> 4;
    const int srow = lane >> 3, scol = (lane & 7) * 8;
    const int NT = K >> 6;

    auto stage = [&](int tt) {
        unsigned short* dst = &lds[(tt & 1) << 15];
        const int kt = tt << 6;
        #pragma unroll
        for (int j = 0; j < 4; ++j) {
            const int cc = w * 4 + j;
            const int row = cc * 8 + srow;
            const size_t aoff = (size_t)(m0 + row) * K + kt + scol;
            const size_t boff = (size_t)(n0 + row) * K + kt + scol;
            gload_lds16(Ahi + aoff,  dst + 0 * 8192 + cc * 512);
            gload_lds16(Alo + aoff,  dst + 1 * 8192 + cc * 512);
            gload_lds16(Bthi + boff, dst + 2 * 8192 + cc * 512);
            gload_lds16(Btlo + boff, dst + 3 * 8192 + cc * 512);
        }
    };

    // per-lane ds_read byte addresses (row&7 == col&7 for fragment rows)
    const unsigned ldsb = (unsigned)(size_t)(lds_us_t*)lds;
    const unsigned skb0 = 2u * (unsigned)(oct ^ ((col & 7) << 3));
    const unsigned skb1 = 2u * (unsigned)((32 + oct) ^ ((col & 7) << 3));
    const unsigned aB = ldsb + 2u * (unsigned)((wm * 64 + col) * 64);
    const unsigned bB = ldsb + 32768u + 2u * (unsigned)((wn * 64 + col) * 64);

    f32x4 acc[4][4] = {};

    stage(0);
    stage(1);   // NT >= 2 always (K = 1024)

    for (int tt = 0; tt < NT; ++tt) {
        if (tt + 1 < NT) asm volatile("s_waitcnt vmcnt(16)" ::: "memory");
        else             asm volatile("s_waitcnt vmcnt(0)" ::: "memory");
        __builtin_amdgcn_s_barrier();            // buf tt&1 fully published
        __builtin_amdgcn_sched_barrier(0);
        const unsigned bo = (unsigned)((tt & 1) << 16);   // byte offset of buffer

        bf16x8 ah[2][4], al[2][4], bh[2][4], bl[2][4];
        #pragma unroll
        for (int kh = 0; kh < 2; ++kh) {
            const unsigned skb = kh ? skb1 : skb0;
            #pragma unroll
            for (int i = 0; i < 4; ++i) {
                ah[kh][i] = dsr128(aB + bo + i * 2048u + skb);
                al[kh][i] = dsr128(aB + bo + i * 2048u + skb + 16384u);
            }
            #pragma unroll
            for (int i = 0; i < 4; ++i) {
                bh[kh][i] = dsr128(bB + bo + i * 2048u + skb);
                bl[kh][i] = dsr128(bB + bo + i * 2048u + skb + 16384u);
            }
        }
        asm volatile("s_waitcnt lgkmcnt(15)" ::: "memory");   // kh0's 16 reads done (4-bit field, max 15)
        __builtin_amdgcn_sched_barrier(0);                     // rule #18
        __builtin_amdgcn_s_setprio(1);
        #pragma unroll
        for (int mi = 0; mi < 4; ++mi)
            #pragma unroll
            for (int nj = 0; nj < 4; ++nj) {
                acc[mi][nj] = mfma_bf16(ah[0][mi], bh[0][nj], acc[mi][nj]);
                acc[mi][nj] = mfma_bf16(ah[0][mi], bl[0][nj], acc[mi][nj]);
                acc[mi][nj] = mfma_bf16(al[0][mi], bh[0][nj], acc[mi][nj]);
            }
        asm volatile("s_waitcnt lgkmcnt(0)" ::: "memory");     // kh1 reads done
        __builtin_amdgcn_sched_barrier(0);
        #pragma unroll
        for (int mi = 0; mi < 4; ++mi)
            #pragma unroll
            for (int nj = 0; nj < 4; ++nj) {
                acc[mi][nj] = mfma_bf16(ah[1][mi], bh[1][nj], acc[mi][nj]);
                acc[mi][nj] = mfma_bf16(ah[1][mi], bl[1][nj], acc[mi][nj]);
                acc[mi][nj] = mfma_bf16(al[1][mi], bh[1][nj], acc[mi][nj]);
            }
        __builtin_amdgcn_s_setprio(0);
        __builtin_amdgcn_s_barrier();            // all reads of buf tt&1 done
        __builtin_amdgcn_sched_barrier(0);       // pin stage below the barrier
        if (tt + 2 < NT) stage(tt + 2);          // overwrite buf tt&1
    }

    // ---- epilogue: per-wave LDS transpose -> coalesced stores (r5 proven) ----
    __syncthreads();
    float* ow = (float*)&lds[w * 8192];   // [64][64] fp32 per wave
    #pragma unroll
    for (int mi = 0; mi < 4; ++mi)
        #pragma unroll
        for (int nj = 0; nj < 4; ++nj)
            #pragma unroll
            for (int r = 0; r < 4; ++r)
                ow[(mi * 16 + g * 4 + r) * 64 + nj * 16 + col] = acc[mi][nj][r];
    __builtin_amdgcn_wave_barrier();

    const int nc = (lane & 7) * 8;
    const int nabs = n0 + wn * 64 + nc;
    f32x4 bi0 = *(const f32x4*)&bias[nabs];
    f32x4 bi1 = *(const f32x4*)&bias[nabs + 4];
    #pragma unroll
    for (int it = 0; it < 8; ++it) {
        const int rl = it * 8 + (lane >> 3);
        f32x4 v0 = *(const f32x4*)&ow[rl * 64 + nc];
        f32x4 v1 = *(const f32x4*)&ow[rl * 64 + nc + 4];
        v0 += bi0; v1 += bi1;
        const int m = m0 + wm * 64 + rl;
        if (OUTMODE == 0) {
            *(f32x4*)&Cf[(size_t)m * N + nabs] = v0;
            *(f32x4*)&Cf[(size_t)m * N + nabs + 4] = v1;
        } else {
            ushort8 hi, lo;
            split2x4(v0, v1, hi, lo);
            const int chunk = (lane & 7) ^ (m & 7);
            const size_t off = (size_t)m * N + n0 + wn * 64 + chunk * 8;
            *(ushort8*)&Ohi[off] = hi;
            *(ushort8*)&Olo[off] = lo;
        }
    }
}

// ---------------------------------------------------------------------------
// V suffix tile sums (vectorized): tsum[h][t][d] = sum_{k in tile t} V[k][d]
// ---------------------------------------------------------------------------
__global__ __launch_bounds__(256) void vsuf_part_kernel(
    const unsigned short* __restrict__ qh, const unsigned short* __restrict__ ql,
    float* __restrict__ tsum)
{
    const int h = blockIdx.x, tg = blockIdx.y;    // grid (16, 8)
    const int tl = threadIdx.x >> 6, lane = threadIdx.x & 63;
    const int t = tg * 4 + tl;
    const int dgrp = lane & 7, rr = lane >> 3;
    const int colbase = h * 192 + 128;
    float sacc[8] = {};
    for (int kk = 0; kk < 8; ++kk) {
        const int row = t * 64 + rr + kk * 8;
        const size_t off = (size_t)row * 3072 + colbase + ((dgrp ^ rr) << 3);
        ushort8 vh = *(const ushort8*)&qh[off];
        ushort8 vl = *(const ushort8*)&ql[off];
        #pragma unroll
        for (int e = 0; e < 8; ++e) sacc[e] += bf2f(vh[e]) + bf2f(vl[e]);
    }
    #pragma unroll
    for (int off = 8; off < 64; off <<= 1)
        #pragma unroll
        for (int e = 0; e < 8; ++e) sacc[e] += __shfl_xor(sacc[e], off);
    if (rr == 0) {
        float* dst = &tsum[((size_t)h * 32 + t) * 64 + dgrp * 8];
        f32x4 v0, v1;
        #pragma unroll
        for (int e = 0; e < 4; ++e) { v0[e] = sacc[e]; v1[e] = sacc[4 + e]; }
        *(f32x4*)dst = v0;
        *(f32x4*)(dst + 4) = v1;
    }
}

__global__ __launch_bounds__(64) void vsuf_scan_kernel(
    const float* __restrict__ tsum, float* __restrict__ vsuf)
{
    const int h = blockIdx.x, d = threadIdx.x;    // 16 blocks x 64 thr
    float acc = 0.f;
    vsuf[((size_t)h * 33 + 32) * 64 + d] = 0.f;
    for (int t = 31; t >= 0; --t) {
        acc += tsum[((size_t)h * 32 + t) * 64 + d];
        vsuf[((size_t)h * 33 + t) * 64 + d] = acc;
    }
}

// ---------------------------------------------------------------------------
// Causal-skip MFMA flash attention with key-range segmentation. (r4/r5 proven)
// ---------------------------------------------------------------------------
__global__ __launch_bounds__(256, 4) void attn_kernel(
    const unsigned short* __restrict__ qh, const unsigned short* __restrict__ ql,
    const float* __restrict__ vsuf,
    unsigned short* __restrict__ ohi, unsigned short* __restrict__ olo,
    float* __restrict__ partO, float* __restrict__ partML,
    int brow)
{
    __shared__ __align__(16) unsigned short lds[16384];   // 32 KB

    const int tid = threadIdx.x, lane = tid & 63, w = tid >> 6;
    const int g = lane >> 4, oct = g * 8, col = lane & 15;
    const int h = blockIdx.y;
    const int kp = tid & 31, dg = tid >> 5;

    const int job = blockIdx.x;
    int i = job, s = 0, slot = -1;
    if (job >= 10) {
        int r = job - 10, cum = 0;
        for (int ii = 10; ii < 32; ++ii) {
            const int ns = (ii + 10) / 10;
            if (r < cum + ns) { i = ii; s = r - cum; break; }
            cum += ns;
        }
        slot = (size_t)0 + h * 58 + (job - 10);
    }
    const int q0 = i * 64;
    const int ntile_all = i + 1;
    const int t_begin = s * 10;
    const int t_end = (slot < 0) ? ntile_all : min(t_begin + 10, ntile_all);
    const bool isseg = (slot >= 0);

    auto kissue = [&](int ktbase, ushort8* kr) {
        #pragma unroll
        for (int j = 0; j < 4; ++j) {
            const int cc = w * 4 + j;
            const unsigned short* src = (cc < 8) ? qh : ql;
            const int row = ktbase + (cc & 7) * 8 + (lane >> 3);
            kr[j] = *(const ushort8*)(src + (size_t)row * 3072 + h * 192 + 64 + (lane & 7) * 8);
        }
    };
    auto kwrite = [&](const ushort8* kr) {
        #pragma unroll
        for (int j = 0; j < 4; ++j) {
            const int cc = w * 4 + j;
            *(ushort8*)&lds[(cc < 8 ? 0 : 4096) + (cc & 7) * 512 + lane * 8] = kr[j];
        }
    };
    auto vload = [&](int ktbase, bf16x8& vA, bf16x8& vB) {
        const int r0 = ktbase + 2 * kp, r1 = r0 + 1;
        const int pA = dg ^ (r0 & 7), pB = dg ^ (r1 & 7);
        vA = *(const bf16x8*)&qh[(size_t)r0 * 3072 + h * 192 + 128 + pA * 8];
        vB = *(const bf16x8*)&qh[(size_t)r1 * 3072 + h * 192 + 128 + pB * 8];
    };
    auto vwrite = [&](bf16x8 vA, bf16x8 vB) {
        #pragma unroll
        for (int e = 0; e < 8; ++e) {
            const int d = dg * 8 + e;
            bf16x2 pr; pr[0] = vA[e]; pr[1] = vB[e];
            *(bf16x2*)&lds[8192 + SWZ(d, 2 * kp)] = pr;
        }
    };

    #pragma unroll
    for (int j = 0; j < 4; ++j) {
        const int cc = w * 4 + j;
        const unsigned short* src = (cc < 8) ? qh : ql;
        const int c7 = cc & 7;
        const int row = q0 + c7 * 8 + (lane >> 3);
        gload_lds16(src + (size_t)row * 3072 + h * 192 + (lane & 7) * 8,
                    &lds[(cc < 8 ? 0 : 4096) + c7 * 512]);
    }
    ushort8 kr[4]; bf16x8 vA, vB;
    kissue(t_begin * 64, kr);
    vload(t_begin * 64, vA, vB);
    __syncthreads();
    bf16x8 qfh[2], qfl[2];
    {
        const int qrow = w * 16 + col;
        qfh[0] = *(const bf16x8*)&lds[SWZ(qrow, oct)];
        qfh[1] = *(const bf16x8*)&lds[SWZ(qrow, 32 + oct)];
        qfl[0] = *(const bf16x8*)&lds[4096 + SWZ(qrow, oct)];
        qfl[1] = *(const bf16x8*)&lds[4096 + SWZ(qrow, 32 + oct)];
    }
    __syncthreads();
    kwrite(kr);
    vwrite(vA, vB);
    __syncthreads();

    const int qg = q0 + w * 16 + col;
    float m_run = isseg ? -INFINITY : 0.f;
    float l_run = 0.f;
    f32x4 oacc[4] = {};

    for (int t = t_begin; t < t_end; ++t) {
        const int kt = t * 64;
        const bool pf = (t + 1 < t_end);
        if (pf) { kissue(kt + 64, kr); vload(kt + 64, vA, vB); }

        f32x4 sacc[4] = {};
        #pragma unroll
        for (int c = 0; c < 2; ++c)
            #pragma unroll
            for (int t4 = 0; t4 < 4; ++t4) {
                const int krow = t4 * 16 + col;
                bf16x8 kh = *(const bf16x8*)&lds[SWZ(krow, c * 32 + oct)];
                bf16x8 kl = *(const bf16x8*)&lds[4096 + SWZ(krow, c * 32 + oct)];
                sacc[t4] = mfma_bf16(kh, qfh[c], sacc[t4]);
                sacc[t4] = mfma_bf16(kh, qfl[c], sacc[t4]);
                sacc[t4] = mfma_bf16(kl, qfh[c], sacc[t4]);
            }

        float p[16];
        float mx = -INFINITY;
        if (t == ntile_all - 1) {
            #pragma unroll
            for (int t4 = 0; t4 < 4; ++t4)
                #pragma unroll
                for (int r = 0; r < 4; ++r) {
                    float sv = sacc[t4][r] * 0.125f;
                    if (kt + t4 * 16 + g * 4 + r > qg) sv = 0.0f;
                    p[t4 * 4 + r] = sv; mx = fmaxf(mx, sv);
                }
        } else {
            #pragma unroll
            for (int t4 = 0; t4 < 4; ++t4)
                #pragma unroll
                for (int r = 0; r < 4; ++r) {
                    float sv = sacc[t4][r] * 0.125f;
                    p[t4 * 4 + r] = sv; mx = fmaxf(mx, sv);
                }
        }
        mx = fmaxf(mx, __shfl_xor(mx, 16));
        mx = fmaxf(mx, __shfl_xor(mx, 32));
        const float mnew = fmaxf(m_run, mx);
        const float corr = __expf(m_run - mnew);
        float ls = 0.f;
        unsigned short* Pw = &lds[12288 + w * 1024];
        #pragma unroll
        for (int t4 = 0; t4 < 4; ++t4)
            #pragma unroll
            for (int rp = 0; rp < 2; ++rp) {
                float e0 = __expf(p[t4 * 4 + rp * 2] - mnew);
                float e1 = __expf(p[t4 * 4 + rp * 2 + 1] - mnew);
                ls += e0 + e1;
                bf16x2 pk; pk[0] = (__bf16)e0; pk[1] = (__bf16)e1;
                *(bf16x2*)&Pw[SWZ(col, t4 * 16 + g * 4 + rp * 2)] = pk;
            }
        ls += __shfl_xor(ls, 16);
        ls += __shfl_xor(ls, 32);
        l_run = l_run * corr + ls;
        m_run = mnew;

        __builtin_amdgcn_wave_barrier();

        __syncthreads();                 // (A)
        if (pf) kwrite(kr);

        #pragma unroll
        for (int dt = 0; dt < 4; ++dt) {
            oacc[dt][0] *= corr; oacc[dt][1] *= corr;
            oacc[dt][2] *= corr; oacc[dt][3] *= corr;
        }
        #pragma unroll
        for (int c = 0; c < 2; ++c) {
            bf16x8 pfv = *(const bf16x8*)&Pw[SWZ(col, c * 32 + oct)];
            #pragma unroll
            for (int dt = 0; dt < 4; ++dt) {
                bf16x8 vh = *(const bf16x8*)&lds[8192 + SWZ(dt * 16 + col, c * 32 + oct)];
                oacc[dt] = mfma_bf16(vh, pfv, oacc[dt]);
            }
        }

        __syncthreads();                 // (B)
        if (pf) vwrite(vA, vB);
    }

    if (isseg) {
        float* po = partO + (size_t)slot * 4096;
        #pragma unroll
        for (int dt = 0; dt < 4; ++dt)
            #pragma unroll
            for (int r = 0; r < 4; ++r)
                po[(dt * 16 + g * 4 + r) * 64 + w * 16 + col] = oacc[dt][r];
        if (g == 0) {
            partML[(size_t)slot * 128 + w * 16 + col] = m_run;
            partML[(size_t)slot * 128 + 64 + w * 16 + col] = l_run;
        }
        return;
    }

    {
        const float wt = __expf(-m_run);
        l_run += (float)(S_ - q0 - 64) * wt;
        const float* vs = vsuf + ((size_t)h * 33 + (i + 1)) * 64;
        #pragma unroll
        for (int dt = 0; dt < 4; ++dt)
            #pragma unroll
            for (int r = 0; r < 4; ++r)
                oacc[dt][r] += wt * vs[dt * 16 + g * 4 + r];
    }
    const float inv = 1.f / l_run;
    float* ow = (float*)&lds[w * 4096];
    const int q = lane >> 2, jj = lane & 3;
    #pragma unroll
    for (int half = 0; half < 2; ++half) {
        __builtin_amdgcn_wave_barrier();
        #pragma unroll
        for (int t4 = 0; t4 < 2; ++t4)
            #pragma unroll
            for (int r = 0; r < 4; ++r)
                ow[col * 40 + t4 * 16 + g * 4 + r] = oacc[half * 2 + t4][r] * inv;
        __builtin_amdgcn_wave_barrier();
        f32x4 v0 = *(const f32x4*)&ow[q * 40 + jj * 8];
        f32x4 v1 = *(const f32x4*)&ow[q * 40 + jj * 8 + 4];
        ushort8 hi, lo;
        split2x4(v0, v1, hi, lo);
        const int m = brow + q0 + w * 16 + q;
        const int chunk = (half * 4 + jj) ^ (m & 7);
        const size_t off = (size_t)m * 1024 + h * 64 + chunk * 8;
        *(ushort8*)&ohi[off] = hi;
        *(ushort8*)&olo[off] = lo;
    }
}

// ---------------------------------------------------------------------------
// Combine partials for split q-tiles (i>=10). (r4/r5 proven)
// ---------------------------------------------------------------------------
__global__ __launch_bounds__(256) void attn_combine_kernel(
    const float* __restrict__ partO, const float* __restrict__ partML,
    const float* __restrict__ vsuf,
    unsigned short* __restrict__ ohi, unsigned short* __restrict__ olo,
    int brow)
{
    const int i = 10 + blockIdx.x;
    const int h = blockIdx.y;
    const int nseg = (i + 10) / 10;
    int cum = 0;
    for (int j = 10; j < i; ++j) cum += (j + 10) / 10;
    const int slot0 = h * 58 + cum;
    const int q = threadIdx.x & 63, dgrp = threadIdx.x >> 6;
    const int q0 = i * 64;

    float mstar = 0.f;
    for (int sg = 0; sg < nseg; ++sg)
        mstar = fmaxf(mstar, partML[(size_t)(slot0 + sg) * 128 + q]);
    const float wtail = __expf(-mstar);
    float lstar = (float)(S_ - q0 - 64) * wtail;

    float od[16];
    const float* vs = vsuf + ((size_t)h * 33 + i + 1) * 64 + dgrp * 16;
    #pragma unroll
    for (int k = 0; k < 16; ++k) od[k] = wtail * vs[k];

    for (int sg = 0; sg < nseg; ++sg) {
        const float ms = partML[(size_t)(slot0 + sg) * 128 + q];
        const float lsv = partML[(size_t)(slot0 + sg) * 128 + 64 + q];
        const float wv = __expf(ms - mstar);
        lstar += lsv * wv;
        const float* po = partO + (size_t)(slot0 + sg) * 4096 + (size_t)(dgrp * 16) * 64 + q;
        #pragma unroll
        for (int k = 0; k < 16; ++k) od[k] += wv * po[k * 64];
    }

    const float inv = 1.f / lstar;
    f32x4 a0, a1, b0, b1;
    #pragma unroll
    for (int k = 0; k < 4; ++k) {
        a0[k] = od[k] * inv; a1[k] = od[4 + k] * inv;
        b0[k] = od[8 + k] * inv; b1[k] = od[12 + k] * inv;
    }
    ushort8 hi0, lo0, hi1, lo1;
    split2x4(a0, a1, hi0, lo0);
    split2x4(b0, b1, hi1, lo1);
    const int mrow = brow + q0 + q;
    const int c0 = (dgrp * 2) ^ (mrow & 7);
    const int c1 = (dgrp * 2 + 1) ^ (mrow & 7);
    const size_t base = (size_t)mrow * 1024 + h * 64;
    *(ushort8*)&ohi[base + c0 * 8] = hi0;
    *(ushort8*)&olo[base + c0 * 8] = lo0;
    *(ushort8*)&ohi[base + c1 * 8] = hi1;
    *(ushort8*)&olo[base + c1 * 8] = lo1;
}

// ---------------------------------------------------------------------------
extern "C" void kernel_launch(void* const* d_in, const int* in_sizes, int n_in,
                              void* d_out, int out_size, void* d_ws, size_t ws_size,
                              hipStream_t stream) {
    const float* x     = (const float*)d_in[0];   // [B,S,D]
    const float* W_qkv = (const float*)d_in[1];   // [D,3D]
    const float* b_qkv = (const float*)d_in[2];   // [3D]
    const float* W_out = (const float*)d_in[3];   // [D,D]
    const float* b_out = (const float*)d_in[4];   // [D]
    float* out = (float*)d_out;                   // [B,S,D]

    unsigned short* us  = (unsigned short*)d_ws;
    unsigned short* Wqh = us;                                  // [3072][1024]
    unsigned short* Wql = Wqh + (size_t)3072 * 1024;
    unsigned short* Woh = Wql + (size_t)3072 * 1024;           // [1024][1024]
    unsigned short* Wol = Woh + (size_t)1024 * 1024;
    unsigned short* XAhi = Wol + (size_t)1024 * 1024;          // [4096][1024] X, then attn-out
    unsigned short* XAlo = XAhi + (size_t)4096 * 1024;

    float* partO  = out;                                       // [928][4096] scratch in d_out
    float* partML = out + (size_t)928 * 4096;                  // [928][128]

    conv_wt_kernel<<<dim3(16, 48), 256, 0, stream>>>(W_qkv, 3072, Wqh, Wql);
    conv_wt_kernel<<<dim3(16, 16), 256, 0, stream>>>(W_out, 1024, Woh, Wol);
    conv_rows_kernel<<<dim3(2048), 256, 0, stream>>>(x, XAhi, XAlo);

    // fused-batch QKV needs 84.2 MB of ws; fall back to per-batch (59 MB) if short
    const size_t need_fused =
        ((size_t)3072 * 1024 * 2 + (size_t)1024 * 1024 * 2 + (size_t)4096 * 1024 * 2 +
         (size_t)4096 * 3072 * 2) * 2 + ((size_t)16 * 32 * 64 + (size_t)16 * 33 * 64) * 4;

    if (ws_size >= need_fused) {
        unsigned short* QKVh = XAlo + (size_t)4096 * 1024;     // [4096][3072] both batches
        unsigned short* QKVl = QKVh + (size_t)4096 * 3072;
        float* tsum = (float*)(QKVl + (size_t)4096 * 3072);    // [16][32][64]
        float* vsuf = tsum + (size_t)16 * 32 * 64;             // [16][33][64]

        gemm_pipe_kernel<1><<<dim3(24, 32), 256, 0, stream>>>(
            XAhi, XAlo, Wqh, Wql, b_qkv, nullptr, QKVh, QKVl, 4096, 3072, 1024);

        for (int b = 0; b < 2; ++b) {
            const size_t qo = (size_t)b * 2048 * 3072;
            vsuf_part_kernel<<<dim3(16, 8), 256, 0, stream>>>(QKVh + qo, QKVl + qo, tsum);
            vsuf_scan_kernel<<<dim3(16), 64, 0, stream>>>(tsum, vsuf);
            attn_kernel<<<dim3(68, 16), 256, 0, stream>>>(
                QKVh + qo, QKVl + qo, vsuf, XAhi, XAlo, partO, partML, b * 2048);
            attn_combine_kernel<<<dim3(22, 16), 256, 0, stream>>>(
                partO, partML, vsuf, XAhi, XAlo, b * 2048);
        }
    } else {
        unsigned short* QKVh = XAlo + (size_t)4096 * 1024;     // [2048][3072] per batch
        unsigned short* QKVl = QKVh + (size_t)2048 * 3072;
        float* tsum = (float*)(QKVl + (size_t)2048 * 3072);
        float* vsuf = tsum + (size_t)16 * 32 * 64;

        for (int b = 0; b < 2; ++b) {
            gemm_pipe_kernel<1><<<dim3(24, 16), 256, 0, stream>>>(
                XAhi + (size_t)b * 2048 * 1024, XAlo + (size_t)b * 2048 * 1024,
                Wqh, Wql, b_qkv, nullptr, QKVh, QKVl, 2048, 3072, 1024);
            vsuf_part_kernel<<<dim3(16, 8), 256, 0, stream>>>(QKVh, QKVl, tsum);
            vsuf_scan_kernel<<<dim3(16), 64, 0, stream>>>(tsum, vsuf);
            attn_kernel<<<dim3(68, 16), 256, 0, stream>>>(
                QKVh, QKVl, vsuf, XAhi, XAlo, partO, partML, b * 2048);
            attn_combine_kernel<<<dim3(22, 16), 256, 0, stream>>>(
                partO, partML, vsuf, XAhi, XAlo, b * 2048);
        }
    }

    gemm_pipe_kernel<0><<<dim3(8, 32), 256, 0, stream>>>(
        XAhi, XAlo, Woh, Wol, b_out, out, nullptr, nullptr, 4096, 1024, 1024);
}

// Round 9
// 189.623 us; speedup vs baseline: 1.5014x; 1.2463x over previous
//
#include <hip/hip_runtime.h>
#include <math.h>

// Problem constants (reference: B=2, S=2048, D=1024, H=16, HD=64)
#define B_ 2
#define S_ 2048
#define D_ 1024
#define H_ 16
#define HD_ 64

typedef unsigned short ushort8 __attribute__((ext_vector_type(8)));
typedef unsigned int u32x4 __attribute__((ext_vector_type(4)));
typedef _Float16 f16x8 __attribute__((ext_vector_type(8)));
typedef _Float16 f16x2 __attribute__((ext_vector_type(2)));
typedef float f32x4 __attribute__((ext_vector_type(4)));

__device__ __forceinline__ unsigned short f2h(float f) {
    union { _Float16 h; unsigned short u; } v;
    v.h = (_Float16)f;                     // native v_cvt_f16_f32, RNE
    return v.u;
}
__device__ __forceinline__ float h2f(unsigned short u) {
    union { unsigned short u; _Float16 h; } v; v.u = u;
    return (float)v.h;
}
// fp16 hi/lo split of 8 fp32 values (residual ~2^-12 relative)
__device__ __forceinline__ void split2x4(f32x4 a, f32x4 b, ushort8& hi, ushort8& lo) {
    #pragma unroll
    for (int i = 0; i < 4; ++i) {
        unsigned short h = f2h(a[i]); hi[i] = h; lo[i] = f2h(a[i] - h2f(h));
    }
    #pragma unroll
    for (int i = 0; i < 4; ++i) {
        unsigned short h = f2h(b[i]); hi[4 + i] = h; lo[4 + i] = f2h(b[i] - h2f(h));
    }
}
__device__ __forceinline__ ushort8 pack2x4h(f32x4 a, f32x4 b) {
    ushort8 hi;
    #pragma unroll
    for (int i = 0; i < 4; ++i) { hi[i] = f2h(a[i]); hi[4 + i] = f2h(b[i]); }
    return hi;
}

// XOR swizzle for [R][64] f16 tiles (128B rows): in-row 16B-chunk permute by row&7.
#define SWZ(row, col) ((((row)) << 6) + (((col)) ^ ((((row)) & 7) << 3)))

__device__ __forceinline__ f32x4 mfma16(f16x8 a, f16x8 b, f32x4 c) {
    return __builtin_amdgcn_mfma_f32_16x16x32_f16(a, b, c, 0, 0, 0);
}

typedef __attribute__((address_space(1))) const void gvoid_t;
typedef __attribute__((address_space(3))) void lvoid_t;
typedef __attribute__((address_space(3))) unsigned short lds_us_t;
__device__ __forceinline__ void gload_lds16(const void* g, void* l) {
    __builtin_amdgcn_global_load_lds((gvoid_t*)g, (lvoid_t*)l, 16, 0, 0);
}
// inline-asm LDS read: opaque to the compiler's waitcnt pass (counted vmcnt survives)
__device__ __forceinline__ f16x8 dsr128(unsigned addr) {
    u32x4 r;
    asm volatile("ds_read_b128 %0, %1" : "=v"(r) : "v"(addr));
    union { u32x4 u; f16x8 h; } cv; cv.u = r; return cv.h;
}

// ---------------------------------------------------------------------------
// conv_rows: fp32 [4096][1024] -> fp16 HI ONLY (A-side of 2-term GEMM),
// pre-swizzled chunks (key = row&7)
// ---------------------------------------------------------------------------
__global__ __launch_bounds__(256) void conv_rows_kernel(
    const float* __restrict__ in, unsigned short* __restrict__ ohi)
{
    const int id = blockIdx.x * 256 + threadIdx.x;   // [0, 4096*128)
    const int r = id >> 7, c = id & 127;
    const float* s = in + (size_t)r * 1024 + c * 8;
    f32x4 v0 = *(const f32x4*)s, v1 = *(const f32x4*)(s + 4);
    ushort8 hi = pack2x4h(v0, v1);
    const int oc = (c & ~7) | ((c ^ r) & 7);
    *(ushort8*)&ohi[(size_t)r * 1024 + oc * 8] = hi;
}

// ---------------------------------------------------------------------------
// conv_wt: W fp32 [1024 k][ldw] -> Wt fp16 h/l [N][1024], transposed +
// pre-swizzled (key = n&7). Grid (K/64, N/64).
// ---------------------------------------------------------------------------
__global__ __launch_bounds__(256) void conv_wt_kernel(
    const float* __restrict__ W, int ldw,
    unsigned short* __restrict__ othi, unsigned short* __restrict__ otlo)
{
    __shared__ float T[64][65];
    const int tid = threadIdx.x;
    const int kx = blockIdx.x * 64, ny = blockIdx.y * 64;
    const int kl = tid >> 2, c0 = (tid & 3) * 16;
    const float* s = W + (size_t)(kx + kl) * ldw + ny + c0;
    #pragma unroll
    for (int i = 0; i < 4; ++i) *(f32x4*)&T[kl][c0 + 4 * i] = *(const f32x4*)(s + 4 * i);
    __syncthreads();
    const int nl = tid >> 2, jj = (tid & 3) * 2;
    #pragma unroll
    for (int p = 0; p < 2; ++p) {
        const int j = jj + p;
        f32x4 a, b;
        #pragma unroll
        for (int i = 0; i < 4; ++i) a[i] = T[j * 8 + i][nl];
        #pragma unroll
        for (int i = 0; i < 4; ++i) b[i] = T[j * 8 + 4 + i][nl];
        ushort8 hi, lo;
        split2x4(a, b, hi, lo);
        const int row = ny + nl;
        const int chunk = blockIdx.x * 8 + (j ^ (nl & 7));
        *(ushort8*)&othi[(size_t)row * 1024 + chunk * 8] = hi;
        *(ushort8*)&otlo[(size_t)row * 1024 + chunk * 8] = lo;
    }
}

// ---------------------------------------------------------------------------
// 2-term fp16 MFMA GEMM: C = Ah @ (Bh + Bl)^T + bias.  (dropped Al·B ~ 2^-12)
// 128x128 tile, BK=64, 256 thr / 4 waves (each 64x64, 64 MFMA : 24 ds_read),
// 2 x 48KB LDS buffers, counted-vmcnt pipeline (r8-proven structure).
// A, Bt fp16 globally pre-swizzled. OUTMODE 0: fp32 C. 1: fp16 h/l.
// ---------------------------------------------------------------------------
template<int OUTMODE>
__global__ __launch_bounds__(256, 1) void gemm_pipe_kernel(
    const unsigned short* __restrict__ Ah,
    const unsigned short* __restrict__ Bth, const unsigned short* __restrict__ Btl,
    const float* __restrict__ bias, float* __restrict__ Cf,
    unsigned short* __restrict__ Ohi, unsigned short* __restrict__ Olo,
    int M, int N, int K)
{
    __shared__ __align__(16) unsigned short lds[49152];   // 2 x 48KB tile buffers

    const int tid = threadIdx.x, lane = tid & 63, w = tid >> 6;
    const int wm = w >> 1, wn = w & 1;
    // XCD-aware bijective swizzle (nwg % 8 == 0 for all grids here)
    const int gx = gridDim.x, nwg = gx * gridDim.y;
    const int lin = blockIdx.y * gx + blockIdx.x;
    const int nl = (lin & 7) * (nwg >> 3) + (lin >> 3);
    const int m0 = (nl / gx) * 128, n0 = (nl % gx) * 128;
    const int col = lane & 15, oct = (lane >> 4) * 8, g = lane >> 4;
    const int srow = lane >> 3, scol = (lane & 7) * 8;
    const int NT = K >> 6;

    // stage: 12 gloads/thread -> regions [Ah][Bh][Bl], 8192 shorts each
    auto stage = [&](int tt) {
        unsigned short* dst = &lds[(tt & 1) * 24576];
        const int kt = tt << 6;
        #pragma unroll
        for (int j = 0; j < 4; ++j) {
            const int cc = w * 4 + j;
            const int row = cc * 8 + srow;
            const size_t aoff = (size_t)(m0 + row) * K + kt + scol;
            const size_t boff = (size_t)(n0 + row) * K + kt + scol;
            gload_lds16(Ah + aoff,  dst + 0 * 8192 + cc * 512);
            gload_lds16(Bth + boff, dst + 1 * 8192 + cc * 512);
            gload_lds16(Btl + boff, dst + 2 * 8192 + cc * 512);
        }
    };

    const unsigned ldsb = (unsigned)(size_t)(lds_us_t*)lds;
    const unsigned skb0 = 2u * (unsigned)(oct ^ ((col & 7) << 3));
    const unsigned skb1 = 2u * (unsigned)((32 + oct) ^ ((col & 7) << 3));
    const unsigned aB = ldsb + 2u * (unsigned)((wm * 64 + col) * 64);
    const unsigned bB = ldsb + 16384u + 2u * (unsigned)((wn * 64 + col) * 64);

    f32x4 acc[4][4] = {};

    stage(0);
    stage(1);   // NT >= 2 always (K = 1024)

    for (int tt = 0; tt < NT; ++tt) {
        if (tt + 1 < NT) asm volatile("s_waitcnt vmcnt(12)" ::: "memory");
        else             asm volatile("s_waitcnt vmcnt(0)" ::: "memory");
        __builtin_amdgcn_s_barrier();            // buf tt&1 fully published
        __builtin_amdgcn_sched_barrier(0);
        const unsigned bo = (unsigned)((tt & 1) * 49152);   // byte offset of buffer

        f16x8 ah[2][4], bhf[2][4], blf[2][4];
        #pragma unroll
        for (int kh = 0; kh < 2; ++kh) {
            const unsigned skb = kh ? skb1 : skb0;
            #pragma unroll
            for (int i = 0; i < 4; ++i) ah[kh][i]  = dsr128(aB + bo + i * 2048u + skb);
            #pragma unroll
            for (int i = 0; i < 4; ++i) bhf[kh][i] = dsr128(bB + bo + i * 2048u + skb);
            #pragma unroll
            for (int i = 0; i < 4; ++i) blf[kh][i] = dsr128(bB + bo + i * 2048u + skb + 16384u);
        }
        asm volatile("s_waitcnt lgkmcnt(12)" ::: "memory");   // kh0's 12 reads done
        __builtin_amdgcn_sched_barrier(0);                     // rule #18
        __builtin_amdgcn_s_setprio(1);
        #pragma unroll
        for (int mi = 0; mi < 4; ++mi)
            #pragma unroll
            for (int nj = 0; nj < 4; ++nj) {
                acc[mi][nj] = mfma16(ah[0][mi], bhf[0][nj], acc[mi][nj]);
                acc[mi][nj] = mfma16(ah[0][mi], blf[0][nj], acc[mi][nj]);
            }
        asm volatile("s_waitcnt lgkmcnt(0)" ::: "memory");     // kh1 reads done
        __builtin_amdgcn_sched_barrier(0);
        #pragma unroll
        for (int mi = 0; mi < 4; ++mi)
            #pragma unroll
            for (int nj = 0; nj < 4; ++nj) {
                acc[mi][nj] = mfma16(ah[1][mi], bhf[1][nj], acc[mi][nj]);
                acc[mi][nj] = mfma16(ah[1][mi], blf[1][nj], acc[mi][nj]);
            }
        __builtin_amdgcn_s_setprio(0);
        __builtin_amdgcn_s_barrier();            // all reads of buf tt&1 done
        __builtin_amdgcn_sched_barrier(0);
        if (tt + 2 < NT) stage(tt + 2);
    }

    // ---- epilogue: per-wave LDS transpose -> coalesced stores ----
    __syncthreads();
    float* ow = (float*)&lds[w * 6144];   // [64][...] 12KB fp32 region per wave? use [64][48]
    // 64 rows x 48 floats = 12288 B = fits in 6144 shorts. Use stride 48.
    #pragma unroll
    for (int mi = 0; mi < 4; ++mi)
        #pragma unroll
        for (int nj = 0; nj < 4; ++nj)
            #pragma unroll
            for (int r = 0; r < 4; ++r)
                ow[(mi * 16 + g * 4 + r) * 48 + ((nj * 16 + col) % 48)] = 0.f;  // placeholder (replaced below)
    // NOTE: 64 cols don't fit stride 48; use direct approach instead:
    __syncthreads();
    float* owf = (float*)&lds[w * 8192];   // [64][64] fp32 = 16KB per wave (total 64KB < 96KB)
    #pragma unroll
    for (int mi = 0; mi < 4; ++mi)
        #pragma unroll
        for (int nj = 0; nj < 4; ++nj)
            #pragma unroll
            for (int r = 0; r < 4; ++r)
                owf[(mi * 16 + g * 4 + r) * 64 + nj * 16 + col] = acc[mi][nj][r];
    __builtin_amdgcn_wave_barrier();

    const int nc = (lane & 7) * 8;
    const int nabs = n0 + wn * 64 + nc;
    f32x4 bi0 = *(const f32x4*)&bias[nabs];
    f32x4 bi1 = *(const f32x4*)&bias[nabs + 4];
    #pragma unroll
    for (int it = 0; it < 8; ++it) {
        const int rl = it * 8 + (lane >> 3);
        f32x4 v0 = *(const f32x4*)&owf[rl * 64 + nc];
        f32x4 v1 = *(const f32x4*)&owf[rl * 64 + nc + 4];
        v0 += bi0; v1 += bi1;
        const int m = m0 + wm * 64 + rl;
        if (OUTMODE == 0) {
            *(f32x4*)&Cf[(size_t)m * N + nabs] = v0;
            *(f32x4*)&Cf[(size_t)m * N + nabs + 4] = v1;
        } else {
            ushort8 hi, lo;
            split2x4(v0, v1, hi, lo);
            const int chunk = (lane & 7) ^ (m & 7);
            const size_t off = (size_t)m * N + n0 + wn * 64 + chunk * 8;
            *(ushort8*)&Ohi[off] = hi;
            *(ushort8*)&Olo[off] = lo;
        }
    }
}

// ---------------------------------------------------------------------------
// V suffix tile sums (vectorized): tsum[h][t][d] = sum_{k in tile t} V[k][d]
// ---------------------------------------------------------------------------
__global__ __launch_bounds__(256) void vsuf_part_kernel(
    const unsigned short* __restrict__ qh, const unsigned short* __restrict__ ql,
    float* __restrict__ tsum)
{
    const int h = blockIdx.x, tg = blockIdx.y;    // grid (16, 8)
    const int tl = threadIdx.x >> 6, lane = threadIdx.x & 63;
    const int t = tg * 4 + tl;
    const int dgrp = lane & 7, rr = lane >> 3;
    const int colbase = h * 192 + 128;
    float sacc[8] = {};
    for (int kk = 0; kk < 8; ++kk) {
        const int row = t * 64 + rr + kk * 8;
        const size_t off = (size_t)row * 3072 + colbase + ((dgrp ^ rr) << 3);
        ushort8 vh = *(const ushort8*)&qh[off];
        ushort8 vl = *(const ushort8*)&ql[off];
        #pragma unroll
        for (int e = 0; e < 8; ++e) sacc[e] += h2f(vh[e]) + h2f(vl[e]);
    }
    #pragma unroll
    for (int off = 8; off < 64; off <<= 1)
        #pragma unroll
        for (int e = 0; e < 8; ++e) sacc[e] += __shfl_xor(sacc[e], off);
    if (rr == 0) {
        float* dst = &tsum[((size_t)h * 32 + t) * 64 + dgrp * 8];
        f32x4 v0, v1;
        #pragma unroll
        for (int e = 0; e < 4; ++e) { v0[e] = sacc[e]; v1[e] = sacc[4 + e]; }
        *(f32x4*)dst = v0;
        *(f32x4*)(dst + 4) = v1;
    }
}

__global__ __launch_bounds__(64) void vsuf_scan_kernel(
    const float* __restrict__ tsum, float* __restrict__ vsuf)
{
    const int h = blockIdx.x, d = threadIdx.x;    // 16 blocks x 64 thr
    float acc = 0.f;
    vsuf[((size_t)h * 33 + 32) * 64 + d] = 0.f;
    for (int t = 31; t >= 0; --t) {
        acc += tsum[((size_t)h * 32 + t) * 64 + d];
        vsuf[((size_t)h * 33 + t) * 64 + d] = acc;
    }
}

// ---------------------------------------------------------------------------
// Causal-skip MFMA flash attention with key-range segmentation (r4-r8 proven
// structure), now fp16: QK^T 2-term (Kh·Qh + Kh·Ql), PV 1-term fp16.
// ---------------------------------------------------------------------------
__global__ __launch_bounds__(256, 4) void attn_kernel(
    const unsigned short* __restrict__ qh, const unsigned short* __restrict__ ql,
    const float* __restrict__ vsuf,
    unsigned short* __restrict__ ohi,
    float* __restrict__ partO, float* __restrict__ partML,
    int brow)
{
    __shared__ __align__(16) unsigned short lds[16384];   // 32 KB
    // [0,4096): K-hi   [8192,12288): Vt-hi   [12288,16384): Ps
    // Q staging aliases [0,8192) before the main loop.

    const int tid = threadIdx.x, lane = tid & 63, w = tid >> 6;
    const int g = lane >> 4, oct = g * 8, col = lane & 15;
    const int h = blockIdx.y;
    const int kp = tid & 31, dg = tid >> 5;

    const int job = blockIdx.x;
    int i = job, s = 0, slot = -1;
    if (job >= 10) {
        int r = job - 10, cum = 0;
        for (int ii = 10; ii < 32; ++ii) {
            const int ns = (ii + 10) / 10;
            if (r < cum + ns) { i = ii; s = r - cum; break; }
            cum += ns;
        }
        slot = (size_t)0 + h * 58 + (job - 10);
    }
    const int q0 = i * 64;
    const int ntile_all = i + 1;
    const int t_begin = s * 10;
    const int t_end = (slot < 0) ? ntile_all : min(t_begin + 10, ntile_all);
    const bool isseg = (slot >= 0);

    auto kissue = [&](int ktbase, ushort8* kr) {
        #pragma unroll
        for (int j = 0; j < 2; ++j) {
            const int cc = w * 2 + j;                 // 0..7
            const int row = ktbase + cc * 8 + (lane >> 3);
            kr[j] = *(const ushort8*)(qh + (size_t)row * 3072 + h * 192 + 64 + (lane & 7) * 8);
        }
    };
    auto kwrite = [&](const ushort8* kr) {
        #pragma unroll
        for (int j = 0; j < 2; ++j) {
            const int cc = w * 2 + j;
            *(ushort8*)&lds[cc * 512 + lane * 8] = kr[j];
        }
    };
    auto vload = [&](int ktbase, f16x8& vA, f16x8& vB) {
        const int r0 = ktbase + 2 * kp, r1 = r0 + 1;
        const int pA = dg ^ (r0 & 7), pB = dg ^ (r1 & 7);
        vA = *(const f16x8*)&qh[(size_t)r0 * 3072 + h * 192 + 128 + pA * 8];
        vB = *(const f16x8*)&qh[(size_t)r1 * 3072 + h * 192 + 128 + pB * 8];
    };
    auto vwrite = [&](f16x8 vA, f16x8 vB) {
        #pragma unroll
        for (int e = 0; e < 8; ++e) {
            const int d = dg * 8 + e;
            f16x2 pr; pr[0] = vA[e]; pr[1] = vB[e];
            *(f16x2*)&lds[8192 + SWZ(d, 2 * kp)] = pr;
        }
    };

    // ---- stage Q tile (h and l; pre-swizzled global -> linear LDS) ----
    #pragma unroll
    for (int j = 0; j < 4; ++j) {
        const int cc = w * 4 + j;
        const unsigned short* src = (cc < 8) ? qh : ql;
        const int c7 = cc & 7;
        const int row = q0 + c7 * 8 + (lane >> 3);
        gload_lds16(src + (size_t)row * 3072 + h * 192 + (lane & 7) * 8,
                    &lds[(cc < 8 ? 0 : 4096) + c7 * 512]);
    }
    ushort8 kr[2]; f16x8 vA, vB;
    kissue(t_begin * 64, kr);
    vload(t_begin * 64, vA, vB);
    __syncthreads();
    f16x8 qfh[2], qfl[2];
    {
        const int qrow = w * 16 + col;
        qfh[0] = *(const f16x8*)&lds[SWZ(qrow, oct)];
        qfh[1] = *(const f16x8*)&lds[SWZ(qrow, 32 + oct)];
        qfl[0] = *(const f16x8*)&lds[4096 + SWZ(qrow, oct)];
        qfl[1] = *(const f16x8*)&lds[4096 + SWZ(qrow, 32 + oct)];
    }
    __syncthreads();
    kwrite(kr);
    vwrite(vA, vB);
    __syncthreads();

    const int qg = q0 + w * 16 + col;
    float m_run = isseg ? -INFINITY : 0.f;
    float l_run = 0.f;
    f32x4 oacc[4] = {};

    for (int t = t_begin; t < t_end; ++t) {
        const int kt = t * 64;
        const bool pf = (t + 1 < t_end);
        if (pf) { kissue(kt + 64, kr); vload(kt + 64, vA, vB); }

        // ---- scores: S^T[key][q] = K·Q (2-term fp16) ----
        f32x4 sacc[4] = {};
        #pragma unroll
        for (int c = 0; c < 2; ++c)
            #pragma unroll
            for (int t4 = 0; t4 < 4; ++t4) {
                const int krow = t4 * 16 + col;
                f16x8 khf = *(const f16x8*)&lds[SWZ(krow, c * 32 + oct)];
                sacc[t4] = mfma16(khf, qfh[c], sacc[t4]);
                sacc[t4] = mfma16(khf, qfl[c], sacc[t4]);
            }

        float p[16];
        float mx = -INFINITY;
        if (t == ntile_all - 1) {
            #pragma unroll
            for (int t4 = 0; t4 < 4; ++t4)
                #pragma unroll
                for (int r = 0; r < 4; ++r) {
                    float sv = sacc[t4][r] * 0.125f;
                    if (kt + t4 * 16 + g * 4 + r > qg) sv = 0.0f;
                    p[t4 * 4 + r] = sv; mx = fmaxf(mx, sv);
                }
        } else {
            #pragma unroll
            for (int t4 = 0; t4 < 4; ++t4)
                #pragma unroll
                for (int r = 0; r < 4; ++r) {
                    float sv = sacc[t4][r] * 0.125f;
                    p[t4 * 4 + r] = sv; mx = fmaxf(mx, sv);
                }
        }
        mx = fmaxf(mx, __shfl_xor(mx, 16));
        mx = fmaxf(mx, __shfl_xor(mx, 32));
        const float mnew = fmaxf(m_run, mx);
        const float corr = __expf(m_run - mnew);
        float ls = 0.f;
        unsigned short* Pw = &lds[12288 + w * 1024];
        #pragma unroll
        for (int t4 = 0; t4 < 4; ++t4)
            #pragma unroll
            for (int rp = 0; rp < 2; ++rp) {
                float e0 = __expf(p[t4 * 4 + rp * 2] - mnew);
                float e1 = __expf(p[t4 * 4 + rp * 2 + 1] - mnew);
                ls += e0 + e1;
                f16x2 pk; pk[0] = (_Float16)e0; pk[1] = (_Float16)e1;
                *(f16x2*)&Pw[SWZ(col, t4 * 16 + g * 4 + rp * 2)] = pk;
            }
        ls += __shfl_xor(ls, 16);
        ls += __shfl_xor(ls, 32);
        l_run = l_run * corr + ls;
        m_run = mnew;

        __builtin_amdgcn_wave_barrier();

        __syncthreads();                 // (A)
        if (pf) kwrite(kr);

        #pragma unroll
        for (int dt = 0; dt < 4; ++dt) {
            oacc[dt][0] *= corr; oacc[dt][1] *= corr;
            oacc[dt][2] *= corr; oacc[dt][3] *= corr;
        }
        #pragma unroll
        for (int c = 0; c < 2; ++c) {
            f16x8 pfv = *(const f16x8*)&Pw[SWZ(col, c * 32 + oct)];
            #pragma unroll
            for (int dt = 0; dt < 4; ++dt) {
                f16x8 vh = *(const f16x8*)&lds[8192 + SWZ(dt * 16 + col, c * 32 + oct)];
                oacc[dt] = mfma16(vh, pfv, oacc[dt]);
            }
        }

        __syncthreads();                 // (B)
        if (pf) vwrite(vA, vB);
    }

    if (isseg) {
        float* po = partO + (size_t)slot * 4096;
        #pragma unroll
        for (int dt = 0; dt < 4; ++dt)
            #pragma unroll
            for (int r = 0; r < 4; ++r)
                po[(dt * 16 + g * 4 + r) * 64 + w * 16 + col] = oacc[dt][r];
        if (g == 0) {
            partML[(size_t)slot * 128 + w * 16 + col] = m_run;
            partML[(size_t)slot * 128 + 64 + w * 16 + col] = l_run;
        }
        return;
    }

    {
        const float wt = __expf(-m_run);
        l_run += (float)(S_ - q0 - 64) * wt;
        const float* vs = vsuf + ((size_t)h * 33 + (i + 1)) * 64;
        #pragma unroll
        for (int dt = 0; dt < 4; ++dt)
            #pragma unroll
            for (int r = 0; r < 4; ++r)
                oacc[dt][r] += wt * vs[dt * 16 + g * 4 + r];
    }
    const float inv = 1.f / l_run;
    float* ow = (float*)&lds[w * 4096];
    const int q = lane >> 2, jj = lane & 3;
    #pragma unroll
    for (int half = 0; half < 2; ++half) {
        __builtin_amdgcn_wave_barrier();
        #pragma unroll
        for (int t4 = 0; t4 < 2; ++t4)
            #pragma unroll
            for (int r = 0; r < 4; ++r)
                ow[col * 40 + t4 * 16 + g * 4 + r] = oacc[half * 2 + t4][r] * inv;
        __builtin_amdgcn_wave_barrier();
        f32x4 v0 = *(const f32x4*)&ow[q * 40 + jj * 8];
        f32x4 v1 = *(const f32x4*)&ow[q * 40 + jj * 8 + 4];
        ushort8 hi = pack2x4h(v0, v1);
        const int m = brow + q0 + w * 16 + q;
        const int chunk = (half * 4 + jj) ^ (m & 7);
        *(ushort8*)&ohi[(size_t)m * 1024 + h * 64 + chunk * 8] = hi;
    }
}

// ---------------------------------------------------------------------------
// Combine partials for split q-tiles (i>=10). (r4-r8 proven; fp16 hi output)
// ---------------------------------------------------------------------------
__global__ __launch_bounds__(256) void attn_combine_kernel(
    const float* __restrict__ partO, const float* __restrict__ partML,
    const float* __restrict__ vsuf,
    unsigned short* __restrict__ ohi,
    int brow)
{
    const int i = 10 + blockIdx.x;
    const int h = blockIdx.y;
    const int nseg = (i + 10) / 10;
    int cum = 0;
    for (int j = 10; j < i; ++j) cum += (j + 10) / 10;
    const int slot0 = h * 58 + cum;
    const int q = threadIdx.x & 63, dgrp = threadIdx.x >> 6;
    const int q0 = i * 64;

    float mstar = 0.f;
    for (int sg = 0; sg < nseg; ++sg)
        mstar = fmaxf(mstar, partML[(size_t)(slot0 + sg) * 128 + q]);
    const float wtail = __expf(-mstar);
    float lstar = (float)(S_ - q0 - 64) * wtail;

    float od[16];
    const float* vs = vsuf + ((size_t)h * 33 + i + 1) * 64 + dgrp * 16;
    #pragma unroll
    for (int k = 0; k < 16; ++k) od[k] = wtail * vs[k];

    for (int sg = 0; sg < nseg; ++sg) {
        const float ms = partML[(size_t)(slot0 + sg) * 128 + q];
        const float lsv = partML[(size_t)(slot0 + sg) * 128 + 64 + q];
        const float wv = __expf(ms - mstar);
        lstar += lsv * wv;
        const float* po = partO + (size_t)(slot0 + sg) * 4096 + (size_t)(dgrp * 16) * 64 + q;
        #pragma unroll
        for (int k = 0; k < 16; ++k) od[k] += wv * po[k * 64];
    }

    const float inv = 1.f / lstar;
    f32x4 a0, a1, b0, b1;
    #pragma unroll
    for (int k = 0; k < 4; ++k) {
        a0[k] = od[k] * inv; a1[k] = od[4 + k] * inv;
        b0[k] = od[8 + k] * inv; b1[k] = od[12 + k] * inv;
    }
    ushort8 hi0 = pack2x4h(a0, a1);
    ushort8 hi1 = pack2x4h(b0, b1);
    const int mrow = brow + q0 + q;
    const int c0 = (dgrp * 2) ^ (mrow & 7);
    const int c1 = (dgrp * 2 + 1) ^ (mrow & 7);
    const size_t base = (size_t)mrow * 1024 + h * 64;
    *(ushort8*)&ohi[base + c0 * 8] = hi0;
    *(ushort8*)&ohi[base + c1 * 8] = hi1;
}

// ---------------------------------------------------------------------------
extern "C" void kernel_launch(void* const* d_in, const int* in_sizes, int n_in,
                              void* d_out, int out_size, void* d_ws, size_t ws_size,
                              hipStream_t stream) {
    const float* x     = (const float*)d_in[0];   // [B,S,D]
    const float* W_qkv = (const float*)d_in[1];   // [D,3D]
    const float* b_qkv = (const float*)d_in[2];   // [3D]
    const float* W_out = (const float*)d_in[3];   // [D,D]
    const float* b_out = (const float*)d_in[4];   // [D]
    float* out = (float*)d_out;                   // [B,S,D]

    // ws layout (~76 MB; r8's fused path proved >= 84 MB available)
    unsigned short* us  = (unsigned short*)d_ws;
    unsigned short* Wqh = us;                                  // [3072][1024]
    unsigned short* Wql = Wqh + (size_t)3072 * 1024;
    unsigned short* Woh = Wql + (size_t)3072 * 1024;           // [1024][1024]
    unsigned short* Wol = Woh + (size_t)1024 * 1024;
    unsigned short* XAhi = Wol + (size_t)1024 * 1024;          // [4096][1024] X, then attn-out (hi only)
    unsigned short* QKVh = XAhi + (size_t)4096 * 1024;         // [4096][3072]
    unsigned short* QKVl = QKVh + (size_t)4096 * 3072;
    float* tsum = (float*)(QKVl + (size_t)4096 * 3072);        // [16][32][64]
    float* vsuf = tsum + (size_t)16 * 32 * 64;                 // [16][33][64]

    float* partO  = out;                                       // [928][4096] scratch in d_out
    float* partML = out + (size_t)928 * 4096;                  // [928][128]

    conv_wt_kernel<<<dim3(16, 48), 256, 0, stream>>>(W_qkv, 3072, Wqh, Wql);
    conv_wt_kernel<<<dim3(16, 16), 256, 0, stream>>>(W_out, 1024, Woh, Wol);
    conv_rows_kernel<<<dim3(2048), 256, 0, stream>>>(x, XAhi);

    // fused-batch QKV projection (both batches, M = 4096)
    gemm_pipe_kernel<1><<<dim3(24, 32), 256, 0, stream>>>(
        XAhi, Wqh, Wql, b_qkv, nullptr, QKVh, QKVl, 4096, 3072, 1024);

    for (int b = 0; b < 2; ++b) {
        const size_t qo = (size_t)b * 2048 * 3072;
        vsuf_part_kernel<<<dim3(16, 8), 256, 0, stream>>>(QKVh + qo, QKVl + qo, tsum);
        vsuf_scan_kernel<<<dim3(16), 64, 0, stream>>>(tsum, vsuf);
        attn_kernel<<<dim3(68, 16), 256, 0, stream>>>(
            QKVh + qo, QKVl + qo, vsuf, XAhi, partO, partML, b * 2048);
        attn_combine_kernel<<<dim3(22, 16), 256, 0, stream>>>(
            partO, partML, vsuf, XAhi, b * 2048);
    }

    gemm_pipe_kernel<0><<<dim3(8, 32), 256, 0, stream>>>(
        XAhi, Woh, Wol, b_out, out, nullptr, nullptr, 4096, 1024, 1024);
}

// Round 10
// 182.841 us; speedup vs baseline: 1.5571x; 1.0371x over previous
//
#include <hip/hip_runtime.h>
#include <math.h>

// Problem constants (reference: B=2, S=2048, D=1024, H=16, HD=64)
#define B_ 2
#define S_ 2048
#define D_ 1024
#define H_ 16
#define HD_ 64

typedef unsigned short ushort8 __attribute__((ext_vector_type(8)));
typedef unsigned int u32x4 __attribute__((ext_vector_type(4)));
typedef _Float16 f16x8 __attribute__((ext_vector_type(8)));
typedef _Float16 f16x2 __attribute__((ext_vector_type(2)));
typedef float f32x4 __attribute__((ext_vector_type(4)));

__device__ __forceinline__ unsigned short f2h(float f) {
    union { _Float16 h; unsigned short u; } v;
    v.h = (_Float16)f;                     // native v_cvt_f16_f32, RNE
    return v.u;
}
__device__ __forceinline__ float h2f(unsigned short u) {
    union { unsigned short u; _Float16 h; } v; v.u = u;
    return (float)v.h;
}
// fp16 hi/lo split of 8 fp32 values (residual ~2^-12 relative)
__device__ __forceinline__ void split2x4(f32x4 a, f32x4 b, ushort8& hi, ushort8& lo) {
    #pragma unroll
    for (int i = 0; i < 4; ++i) {
        unsigned short h = f2h(a[i]); hi[i] = h; lo[i] = f2h(a[i] - h2f(h));
    }
    #pragma unroll
    for (int i = 0; i < 4; ++i) {
        unsigned short h = f2h(b[i]); hi[4 + i] = h; lo[4 + i] = f2h(b[i] - h2f(h));
    }
}
__device__ __forceinline__ ushort8 pack2x4h(f32x4 a, f32x4 b) {
    ushort8 hi;
    #pragma unroll
    for (int i = 0; i < 4; ++i) { hi[i] = f2h(a[i]); hi[4 + i] = f2h(b[i]); }
    return hi;
}

// XOR swizzle for [R][64] f16 tiles (128B rows): in-row 16B-chunk permute by row&7.
#define SWZ(row, col) ((((row)) << 6) + (((col)) ^ ((((row)) & 7) << 3)))

__device__ __forceinline__ f32x4 mfma16(f16x8 a, f16x8 b, f32x4 c) {
    return __builtin_amdgcn_mfma_f32_16x16x32_f16(a, b, c, 0, 0, 0);
}

typedef __attribute__((address_space(1))) const void gvoid_t;
typedef __attribute__((address_space(3))) void lvoid_t;
typedef __attribute__((address_space(3))) unsigned short lds_us_t;
__device__ __forceinline__ void gload_lds16(const void* g, void* l) {
    __builtin_amdgcn_global_load_lds((gvoid_t*)g, (lvoid_t*)l, 16, 0, 0);
}
// inline-asm LDS read: opaque to the compiler's waitcnt pass (counted vmcnt survives)
__device__ __forceinline__ f16x8 dsr128(unsigned addr) {
    u32x4 r;
    asm volatile("ds_read_b128 %0, %1" : "=v"(r) : "v"(addr));
    union { u32x4 u; f16x8 h; } cv; cv.u = r; return cv.h;
}

// ---------------------------------------------------------------------------
// conv_rows: fp32 [4096][1024] -> fp16 HI ONLY (A-side of 2-term GEMM),
// pre-swizzled chunks (key = row&7)
// ---------------------------------------------------------------------------
__global__ __launch_bounds__(256) void conv_rows_kernel(
    const float* __restrict__ in, unsigned short* __restrict__ ohi)
{
    const int id = blockIdx.x * 256 + threadIdx.x;   // [0, 4096*128)
    const int r = id >> 7, c = id & 127;
    const float* s = in + (size_t)r * 1024 + c * 8;
    f32x4 v0 = *(const f32x4*)s, v1 = *(const f32x4*)(s + 4);
    ushort8 hi = pack2x4h(v0, v1);
    const int oc = (c & ~7) | ((c ^ r) & 7);
    *(ushort8*)&ohi[(size_t)r * 1024 + oc * 8] = hi;
}

// ---------------------------------------------------------------------------
// conv_wt: W fp32 [1024 k][ldw] -> Wt fp16 h/l [N][1024], transposed +
// pre-swizzled (key = n&7). Grid (K/64, N/64).
// ---------------------------------------------------------------------------
__global__ __launch_bounds__(256) void conv_wt_kernel(
    const float* __restrict__ W, int ldw,
    unsigned short* __restrict__ othi, unsigned short* __restrict__ otlo)
{
    __shared__ float T[64][65];
    const int tid = threadIdx.x;
    const int kx = blockIdx.x * 64, ny = blockIdx.y * 64;
    const int kl = tid >> 2, c0 = (tid & 3) * 16;
    const float* s = W + (size_t)(kx + kl) * ldw + ny + c0;
    #pragma unroll
    for (int i = 0; i < 4; ++i) *(f32x4*)&T[kl][c0 + 4 * i] = *(const f32x4*)(s + 4 * i);
    __syncthreads();
    const int nl = tid >> 2, jj = (tid & 3) * 2;
    #pragma unroll
    for (int p = 0; p < 2; ++p) {
        const int j = jj + p;
        f32x4 a, b;
        #pragma unroll
        for (int i = 0; i < 4; ++i) a[i] = T[j * 8 + i][nl];
        #pragma unroll
        for (int i = 0; i < 4; ++i) b[i] = T[j * 8 + 4 + i][nl];
        ushort8 hi, lo;
        split2x4(a, b, hi, lo);
        const int row = ny + nl;
        const int chunk = blockIdx.x * 8 + (j ^ (nl & 7));
        *(ushort8*)&othi[(size_t)row * 1024 + chunk * 8] = hi;
        *(ushort8*)&otlo[(size_t)row * 1024 + chunk * 8] = lo;
    }
}

// ---------------------------------------------------------------------------
// 2-term fp16 MFMA GEMM: C = Ah @ (Bh + Bl)^T + bias.
// 128x128 tile, BK=32 -> 24KB/tile, 2-buf = 48KB LDS -> 3 blocks/CU
// (12 waves/CU: cross-block overlap feeds the per-CU MFMA pipe through
// barriers). Counted vmcnt(6); split lgkmcnt(4) overlaps Bl reads under
// hi-term MFMAs. BK=32 swizzle: 16B chunk ^= (row&3) within 64B rows
// (2-way bank aliasing = free); staging composes this with the global
// row&7 pre-swizzle in the source address.
// A, Bt fp16 globally pre-swizzled. OUTMODE 0: fp32 C. 1: fp16 h/l.
// ---------------------------------------------------------------------------
template<int OUTMODE>
__global__ __launch_bounds__(256, 3) void gemm_pipe_kernel(
    const unsigned short* __restrict__ Ah,
    const unsigned short* __restrict__ Bth, const unsigned short* __restrict__ Btl,
    const float* __restrict__ bias, float* __restrict__ Cf,
    unsigned short* __restrict__ Ohi, unsigned short* __restrict__ Olo,
    int M, int N, int K)
{
    __shared__ __align__(16) unsigned short lds[24576];   // 48KB: 2 x 24KB buffers
    // per buffer: A [0,8192)B, Bh [8192,16384)B, Bl [16384,24576)B; each [128 rows][4 x 16B chunks]

    const int tid = threadIdx.x, lane = tid & 63, w = tid >> 6;
    const int wm = w >> 1, wn = w & 1;
    // XCD-aware bijective swizzle (nwg % 8 == 0 for all grids here)
    const int gx = gridDim.x, nwg = gx * gridDim.y;
    const int lin = blockIdx.y * gx + blockIdx.x;
    const int nl = (lin & 7) * (nwg >> 3) + (lin >> 3);
    const int m0 = (nl / gx) * 128, n0 = (nl % gx) * 128;
    const int col = lane & 15, g = lane >> 4;
    const int NT = K >> 5;

    // staging roles: instr q covers rows (w*2+q)*16 + (lane>>2), chunk = lane&3
    const int sr0 = (w * 2 + 0) * 16 + (lane >> 2);
    const int sr1 = (w * 2 + 1) * 16 + (lane >> 2);
    const int scp = lane & 3;

    auto stage = [&](int tt) {
        unsigned short* dst = &lds[(tt & 1) * 12288];     // shorts
        const int hi8 = (tt >> 1) * 8;
        const int tb4 = (tt & 1) << 2;
        #pragma unroll
        for (int q = 0; q < 2; ++q) {
            const int r = q ? sr1 : sr0;
            // global phys chunk: (t>>1)*8 + (((t&1)*4) ^ (r&4)) | (chunk), composed swizzle
            const int p = hi8 + ((tb4 ^ (r & 4)) | scp);
            const size_t go = (size_t)p * 8;
            const int slotb = (w * 2 + q) * 512;          // shorts (1KB per wave-instr)
            gload_lds16(Ah  + (size_t)(m0 + r) * 1024 + go, dst + 0    + slotb);
            gload_lds16(Bth + (size_t)(n0 + r) * 1024 + go, dst + 4096 + slotb);
            gload_lds16(Btl + (size_t)(n0 + r) * 1024 + go, dst + 8192 + slotb);
        }
    };

    // per-lane ds_read byte addresses: row*64B + ((kchunk ^ (row&3))<<4)
    const unsigned ldsb = (unsigned)(size_t)(lds_us_t*)lds;
    const unsigned sk = (unsigned)((((lane >> 4) ^ (col & 3)) << 4));
    const unsigned aB  = ldsb + (unsigned)((wm * 64 + col) * 64) + sk;
    const unsigned bBh = ldsb + 8192u  + (unsigned)((wn * 64 + col) * 64) + sk;
    const unsigned bBl = ldsb + 16384u + (unsigned)((wn * 64 + col) * 64) + sk;

    f32x4 acc[4][4] = {};

    stage(0);
    stage(1);   // NT >= 2 always

    for (int tt = 0; tt < NT; ++tt) {
        if (tt + 1 < NT) asm volatile("s_waitcnt vmcnt(6)" ::: "memory");
        else             asm volatile("s_waitcnt vmcnt(0)" ::: "memory");
        __builtin_amdgcn_s_barrier();            // buf tt&1 fully published
        __builtin_amdgcn_sched_barrier(0);
        const unsigned bo = (unsigned)((tt & 1) * 24576);   // byte offset

        f16x8 a[4], bh[4], bl[4];
        #pragma unroll
        for (int i = 0; i < 4; ++i) a[i]  = dsr128(aB + bo + i * 1024u);
        #pragma unroll
        for (int i = 0; i < 4; ++i) bh[i] = dsr128(bBh + bo + i * 1024u);
        #pragma unroll
        for (int i = 0; i < 4; ++i) bl[i] = dsr128(bBl + bo + i * 1024u);

        asm volatile("s_waitcnt lgkmcnt(4)" ::: "memory");  // a[] + bh[] done, bl in flight
        __builtin_amdgcn_sched_barrier(0);                   // rule #18
        __builtin_amdgcn_s_setprio(1);
        #pragma unroll
        for (int mi = 0; mi < 4; ++mi)
            #pragma unroll
            for (int nj = 0; nj < 4; ++nj)
                acc[mi][nj] = mfma16(a[mi], bh[nj], acc[mi][nj]);
        asm volatile("s_waitcnt lgkmcnt(0)" ::: "memory");  // bl[] done
        __builtin_amdgcn_sched_barrier(0);
        #pragma unroll
        for (int mi = 0; mi < 4; ++mi)
            #pragma unroll
            for (int nj = 0; nj < 4; ++nj)
                acc[mi][nj] = mfma16(a[mi], bl[nj], acc[mi][nj]);
        __builtin_amdgcn_s_setprio(0);
        __builtin_amdgcn_s_barrier();            // all reads of buf tt&1 done
        __builtin_amdgcn_sched_barrier(0);
        if (tt + 2 < NT) stage(tt + 2);
    }

    // ---- epilogue: per-wave LDS transpose in two 32-row halves (8KB/wave) ----
    __syncthreads();
    float* ow = (float*)((char*)lds + w * 8192);   // [32][64] fp32 per wave
    const int nc = (lane & 7) * 8;
    const int nabs = n0 + wn * 64 + nc;
    f32x4 bi0 = *(const f32x4*)&bias[nabs];
    f32x4 bi1 = *(const f32x4*)&bias[nabs + 4];
    #pragma unroll
    for (int half = 0; half < 2; ++half) {
        __builtin_amdgcn_wave_barrier();
        #pragma unroll
        for (int ml = 0; ml < 2; ++ml)
            #pragma unroll
            for (int nj = 0; nj < 4; ++nj)
                #pragma unroll
                for (int r = 0; r < 4; ++r)
                    ow[(ml * 16 + g * 4 + r) * 64 + nj * 16 + col] = acc[half * 2 + ml][nj][r];
        __builtin_amdgcn_wave_barrier();
        #pragma unroll
        for (int it = 0; it < 4; ++it) {
            const int rl = it * 8 + (lane >> 3);
            f32x4 v0 = *(const f32x4*)&ow[rl * 64 + nc];
            f32x4 v1 = *(const f32x4*)&ow[rl * 64 + nc + 4];
            v0 += bi0; v1 += bi1;
            const int m = m0 + wm * 64 + half * 32 + rl;
            if (OUTMODE == 0) {
                *(f32x4*)&Cf[(size_t)m * N + nabs] = v0;
                *(f32x4*)&Cf[(size_t)m * N + nabs + 4] = v1;
            } else {
                ushort8 hi, lo;
                split2x4(v0, v1, hi, lo);
                const int chunk = (lane & 7) ^ (m & 7);
                const size_t off = (size_t)m * N + n0 + wn * 64 + chunk * 8;
                *(ushort8*)&Ohi[off] = hi;
                *(ushort8*)&Olo[off] = lo;
            }
        }
        __builtin_amdgcn_wave_barrier();
    }
}

// ---------------------------------------------------------------------------
// V suffix tile sums (vectorized): tsum[h][t][d] = sum_{k in tile t} V[k][d]
// ---------------------------------------------------------------------------
__global__ __launch_bounds__(256) void vsuf_part_kernel(
    const unsigned short* __restrict__ qh, const unsigned short* __restrict__ ql,
    float* __restrict__ tsum)
{
    const int h = blockIdx.x, tg = blockIdx.y;    // grid (16, 8)
    const int tl = threadIdx.x >> 6, lane = threadIdx.x & 63;
    const int t = tg * 4 + tl;
    const int dgrp = lane & 7, rr = lane >> 3;
    const int colbase = h * 192 + 128;
    float sacc[8] = {};
    for (int kk = 0; kk < 8; ++kk) {
        const int row = t * 64 + rr + kk * 8;
        const size_t off = (size_t)row * 3072 + colbase + ((dgrp ^ rr) << 3);
        ushort8 vh = *(const ushort8*)&qh[off];
        ushort8 vl = *(const ushort8*)&ql[off];
        #pragma unroll
        for (int e = 0; e < 8; ++e) sacc[e] += h2f(vh[e]) + h2f(vl[e]);
    }
    #pragma unroll
    for (int off = 8; off < 64; off <<= 1)
        #pragma unroll
        for (int e = 0; e < 8; ++e) sacc[e] += __shfl_xor(sacc[e], off);
    if (rr == 0) {
        float* dst = &tsum[((size_t)h * 32 + t) * 64 + dgrp * 8];
        f32x4 v0, v1;
        #pragma unroll
        for (int e = 0; e < 4; ++e) { v0[e] = sacc[e]; v1[e] = sacc[4 + e]; }
        *(f32x4*)dst = v0;
        *(f32x4*)(dst + 4) = v1;
    }
}

__global__ __launch_bounds__(64) void vsuf_scan_kernel(
    const float* __restrict__ tsum, float* __restrict__ vsuf)
{
    const int h = blockIdx.x, d = threadIdx.x;    // 16 blocks x 64 thr
    float acc = 0.f;
    vsuf[((size_t)h * 33 + 32) * 64 + d] = 0.f;
    for (int t = 31; t >= 0; --t) {
        acc += tsum[((size_t)h * 32 + t) * 64 + d];
        vsuf[((size_t)h * 33 + t) * 64 + d] = acc;
    }
}

// ---------------------------------------------------------------------------
// Causal-skip MFMA flash attention with key-range segmentation (r4-r9 proven),
// fp16: QK^T 2-term (Kh·Qh + Kh·Ql), PV 1-term fp16.
// ---------------------------------------------------------------------------
__global__ __launch_bounds__(256, 4) void attn_kernel(
    const unsigned short* __restrict__ qh, const unsigned short* __restrict__ ql,
    const float* __restrict__ vsuf,
    unsigned short* __restrict__ ohi,
    float* __restrict__ partO, float* __restrict__ partML,
    int brow)
{
    __shared__ __align__(16) unsigned short lds[16384];   // 32 KB

    const int tid = threadIdx.x, lane = tid & 63, w = tid >> 6;
    const int g = lane >> 4, oct = g * 8, col = lane & 15;
    const int h = blockIdx.y;
    const int kp = tid & 31, dg = tid >> 5;

    const int job = blockIdx.x;
    int i = job, s = 0, slot = -1;
    if (job >= 10) {
        int r = job - 10, cum = 0;
        for (int ii = 10; ii < 32; ++ii) {
            const int ns = (ii + 10) / 10;
            if (r < cum + ns) { i = ii; s = r - cum; break; }
            cum += ns;
        }
        slot = (size_t)0 + h * 58 + (job - 10);
    }
    const int q0 = i * 64;
    const int ntile_all = i + 1;
    const int t_begin = s * 10;
    const int t_end = (slot < 0) ? ntile_all : min(t_begin + 10, ntile_all);
    const bool isseg = (slot >= 0);

    auto kissue = [&](int ktbase, ushort8* kr) {
        #pragma unroll
        for (int j = 0; j < 2; ++j) {
            const int cc = w * 2 + j;                 // 0..7
            const int row = ktbase + cc * 8 + (lane >> 3);
            kr[j] = *(const ushort8*)(qh + (size_t)row * 3072 + h * 192 + 64 + (lane & 7) * 8);
        }
    };
    auto kwrite = [&](const ushort8* kr) {
        #pragma unroll
        for (int j = 0; j < 2; ++j) {
            const int cc = w * 2 + j;
            *(ushort8*)&lds[cc * 512 + lane * 8] = kr[j];
        }
    };
    auto vload = [&](int ktbase, f16x8& vA, f16x8& vB) {
        const int r0 = ktbase + 2 * kp, r1 = r0 + 1;
        const int pA = dg ^ (r0 & 7), pB = dg ^ (r1 & 7);
        vA = *(const f16x8*)&qh[(size_t)r0 * 3072 + h * 192 + 128 + pA * 8];
        vB = *(const f16x8*)&qh[(size_t)r1 * 3072 + h * 192 + 128 + pB * 8];
    };
    auto vwrite = [&](f16x8 vA, f16x8 vB) {
        #pragma unroll
        for (int e = 0; e < 8; ++e) {
            const int d = dg * 8 + e;
            f16x2 pr; pr[0] = vA[e]; pr[1] = vB[e];
            *(f16x2*)&lds[8192 + SWZ(d, 2 * kp)] = pr;
        }
    };

    // ---- stage Q tile (h and l; pre-swizzled global -> linear LDS) ----
    #pragma unroll
    for (int j = 0; j < 4; ++j) {
        const int cc = w * 4 + j;
        const unsigned short* src = (cc < 8) ? qh : ql;
        const int c7 = cc & 7;
        const int row = q0 + c7 * 8 + (lane >> 3);
        gload_lds16(src + (size_t)row * 3072 + h * 192 + (lane & 7) * 8,
                    &lds[(cc < 8 ? 0 : 4096) + c7 * 512]);
    }
    ushort8 kr[2]; f16x8 vA, vB;
    kissue(t_begin * 64, kr);
    vload(t_begin * 64, vA, vB);
    __syncthreads();
    f16x8 qfh[2], qfl[2];
    {
        const int qrow = w * 16 + col;
        qfh[0] = *(const f16x8*)&lds[SWZ(qrow, oct)];
        qfh[1] = *(const f16x8*)&lds[SWZ(qrow, 32 + oct)];
        qfl[0] = *(const f16x8*)&lds[4096 + SWZ(qrow, oct)];
        qfl[1] = *(const f16x8*)&lds[4096 + SWZ(qrow, 32 + oct)];
    }
    __syncthreads();
    kwrite(kr);
    vwrite(vA, vB);
    __syncthreads();

    const int qg = q0 + w * 16 + col;
    float m_run = isseg ? -INFINITY : 0.f;
    float l_run = 0.f;
    f32x4 oacc[4] = {};

    for (int t = t_begin; t < t_end; ++t) {
        const int kt = t * 64;
        const bool pf = (t + 1 < t_end);
        if (pf) { kissue(kt + 64, kr); vload(kt + 64, vA, vB); }

        // ---- scores: S^T[key][q] = K·Q (2-term fp16) ----
        f32x4 sacc[4] = {};
        #pragma unroll
        for (int c = 0; c < 2; ++c)
            #pragma unroll
            for (int t4 = 0; t4 < 4; ++t4) {
                const int krow = t4 * 16 + col;
                f16x8 khf = *(const f16x8*)&lds[SWZ(krow, c * 32 + oct)];
                sacc[t4] = mfma16(khf, qfh[c], sacc[t4]);
                sacc[t4] = mfma16(khf, qfl[c], sacc[t4]);
            }

        float p[16];
        float mx = -INFINITY;
        if (t == ntile_all - 1) {
            #pragma unroll
            for (int t4 = 0; t4 < 4; ++t4)
                #pragma unroll
                for (int r = 0; r < 4; ++r) {
                    float sv = sacc[t4][r] * 0.125f;
                    if (kt + t4 * 16 + g * 4 + r > qg) sv = 0.0f;
                    p[t4 * 4 + r] = sv; mx = fmaxf(mx, sv);
                }
        } else {
            #pragma unroll
            for (int t4 = 0; t4 < 4; ++t4)
                #pragma unroll
                for (int r = 0; r < 4; ++r) {
                    float sv = sacc[t4][r] * 0.125f;
                    p[t4 * 4 + r] = sv; mx = fmaxf(mx, sv);
                }
        }
        mx = fmaxf(mx, __shfl_xor(mx, 16));
        mx = fmaxf(mx, __shfl_xor(mx, 32));
        const float mnew = fmaxf(m_run, mx);
        const float corr = __expf(m_run - mnew);
        float ls = 0.f;
        unsigned short* Pw = &lds[12288 + w * 1024];
        #pragma unroll
        for (int t4 = 0; t4 < 4; ++t4)
            #pragma unroll
            for (int rp = 0; rp < 2; ++rp) {
                float e0 = __expf(p[t4 * 4 + rp * 2] - mnew);
                float e1 = __expf(p[t4 * 4 + rp * 2 + 1] - mnew);
                ls += e0 + e1;
                f16x2 pk; pk[0] = (_Float16)e0; pk[1] = (_Float16)e1;
                *(f16x2*)&Pw[SWZ(col, t4 * 16 + g * 4 + rp * 2)] = pk;
            }
        ls += __shfl_xor(ls, 16);
        ls += __shfl_xor(ls, 32);
        l_run = l_run * corr + ls;
        m_run = mnew;

        __builtin_amdgcn_wave_barrier();

        __syncthreads();                 // (A)
        if (pf) kwrite(kr);

        #pragma unroll
        for (int dt = 0; dt < 4; ++dt) {
            oacc[dt][0] *= corr; oacc[dt][1] *= corr;
            oacc[dt][2] *= corr; oacc[dt][3] *= corr;
        }
        #pragma unroll
        for (int c = 0; c < 2; ++c) {
            f16x8 pfv = *(const f16x8*)&Pw[SWZ(col, c * 32 + oct)];
            #pragma unroll
            for (int dt = 0; dt < 4; ++dt) {
                f16x8 vh = *(const f16x8*)&lds[8192 + SWZ(dt * 16 + col, c * 32 + oct)];
                oacc[dt] = mfma16(vh, pfv, oacc[dt]);
            }
        }

        __syncthreads();                 // (B)
        if (pf) vwrite(vA, vB);
    }

    if (isseg) {
        float* po = partO + (size_t)slot * 4096;
        #pragma unroll
        for (int dt = 0; dt < 4; ++dt)
            #pragma unroll
            for (int r = 0; r < 4; ++r)
                po[(dt * 16 + g * 4 + r) * 64 + w * 16 + col] = oacc[dt][r];
        if (g == 0) {
            partML[(size_t)slot * 128 + w * 16 + col] = m_run;
            partML[(size_t)slot * 128 + 64 + w * 16 + col] = l_run;
        }
        return;
    }

    {
        const float wt = __expf(-m_run);
        l_run += (float)(S_ - q0 - 64) * wt;
        const float* vs = vsuf + ((size_t)h * 33 + (i + 1)) * 64;
        #pragma unroll
        for (int dt = 0; dt < 4; ++dt)
            #pragma unroll
            for (int r = 0; r < 4; ++r)
                oacc[dt][r] += wt * vs[dt * 16 + g * 4 + r];
    }
    const float inv = 1.f / l_run;
    float* ow = (float*)&lds[w * 4096];
    const int q = lane >> 2, jj = lane & 3;
    #pragma unroll
    for (int half = 0; half < 2; ++half) {
        __builtin_amdgcn_wave_barrier();
        #pragma unroll
        for (int t4 = 0; t4 < 2; ++t4)
            #pragma unroll
            for (int r = 0; r < 4; ++r)
                ow[col * 40 + t4 * 16 + g * 4 + r] = oacc[half * 2 + t4][r] * inv;
        __builtin_amdgcn_wave_barrier();
        f32x4 v0 = *(const f32x4*)&ow[q * 40 + jj * 8];
        f32x4 v1 = *(const f32x4*)&ow[q * 40 + jj * 8 + 4];
        ushort8 hi = pack2x4h(v0, v1);
        const int m = brow + q0 + w * 16 + q;
        const int chunk = (half * 4 + jj) ^ (m & 7);
        *(ushort8*)&ohi[(size_t)m * 1024 + h * 64 + chunk * 8] = hi;
    }
}

// ---------------------------------------------------------------------------
// Combine partials for split q-tiles (i>=10). (r4-r9 proven; fp16 hi output)
// ---------------------------------------------------------------------------
__global__ __launch_bounds__(256) void attn_combine_kernel(
    const float* __restrict__ partO, const float* __restrict__ partML,
    const float* __restrict__ vsuf,
    unsigned short* __restrict__ ohi,
    int brow)
{
    const int i = 10 + blockIdx.x;
    const int h = blockIdx.y;
    const int nseg = (i + 10) / 10;
    int cum = 0;
    for (int j = 10; j < i; ++j) cum += (j + 10) / 10;
    const int slot0 = h * 58 + cum;
    const int q = threadIdx.x & 63, dgrp = threadIdx.x >> 6;
    const int q0 = i * 64;

    float mstar = 0.f;
    for (int sg = 0; sg < nseg; ++sg)
        mstar = fmaxf(mstar, partML[(size_t)(slot0 + sg) * 128 + q]);
    const float wtail = __expf(-mstar);
    float lstar = (float)(S_ - q0 - 64) * wtail;

    float od[16];
    const float* vs = vsuf + ((size_t)h * 33 + i + 1) * 64 + dgrp * 16;
    #pragma unroll
    for (int k = 0; k < 16; ++k) od[k] = wtail * vs[k];

    for (int sg = 0; sg < nseg; ++sg) {
        const float ms = partML[(size_t)(slot0 + sg) * 128 + q];
        const float lsv = partML[(size_t)(slot0 + sg) * 128 + 64 + q];
        const float wv = __expf(ms - mstar);
        lstar += lsv * wv;
        const float* po = partO + (size_t)(slot0 + sg) * 4096 + (size_t)(dgrp * 16) * 64 + q;
        #pragma unroll
        for (int k = 0; k < 16; ++k) od[k] += wv * po[k * 64];
    }

    const float inv = 1.f / lstar;
    f32x4 a0, a1, b0, b1;
    #pragma unroll
    for (int k = 0; k < 4; ++k) {
        a0[k] = od[k] * inv; a1[k] = od[4 + k] * inv;
        b0[k] = od[8 + k] * inv; b1[k] = od[12 + k] * inv;
    }
    ushort8 hi0 = pack2x4h(a0, a1);
    ushort8 hi1 = pack2x4h(b0, b1);
    const int mrow = brow + q0 + q;
    const int c0 = (dgrp * 2) ^ (mrow & 7);
    const int c1 = (dgrp * 2 + 1) ^ (mrow & 7);
    const size_t base = (size_t)mrow * 1024 + h * 64;
    *(ushort8*)&ohi[base + c0 * 8] = hi0;
    *(ushort8*)&ohi[base + c1 * 8] = hi1;
}

// ---------------------------------------------------------------------------
extern "C" void kernel_launch(void* const* d_in, const int* in_sizes, int n_in,
                              void* d_out, int out_size, void* d_ws, size_t ws_size,
                              hipStream_t stream) {
    const float* x     = (const float*)d_in[0];   // [B,S,D]
    const float* W_qkv = (const float*)d_in[1];   // [D,3D]
    const float* b_qkv = (const float*)d_in[2];   // [3D]
    const float* W_out = (const float*)d_in[3];   // [D,D]
    const float* b_out = (const float*)d_in[4];   // [D]
    float* out = (float*)d_out;                   // [B,S,D]

    // ws layout (~76 MB; proven available in r8/r9)
    unsigned short* us  = (unsigned short*)d_ws;
    unsigned short* Wqh = us;                                  // [3072][1024]
    unsigned short* Wql = Wqh + (size_t)3072 * 1024;
    unsigned short* Woh = Wql + (size_t)3072 * 1024;           // [1024][1024]
    unsigned short* Wol = Woh + (size_t)1024 * 1024;
    unsigned short* XAhi = Wol + (size_t)1024 * 1024;          // [4096][1024] X, then attn-out (hi only)
    unsigned short* QKVh = XAhi + (size_t)4096 * 1024;         // [4096][3072]
    unsigned short* QKVl = QKVh + (size_t)4096 * 3072;
    float* tsum = (float*)(QKVl + (size_t)4096 * 3072);        // [16][32][64]
    float* vsuf = tsum + (size_t)16 * 32 * 64;                 // [16][33][64]

    float* partO  = out;                                       // [928][4096] scratch in d_out
    float* partML = out + (size_t)928 * 4096;                  // [928][128]

    conv_wt_kernel<<<dim3(16, 48), 256, 0, stream>>>(W_qkv, 3072, Wqh, Wql);
    conv_wt_kernel<<<dim3(16, 16), 256, 0, stream>>>(W_out, 1024, Woh, Wol);
    conv_rows_kernel<<<dim3(2048), 256, 0, stream>>>(x, XAhi);

    // fused-batch QKV projection (both batches, M = 4096): grid 768 = 3 blocks/CU
    gemm_pipe_kernel<1><<<dim3(24, 32), 256, 0, stream>>>(
        XAhi, Wqh, Wql, b_qkv, nullptr, QKVh, QKVl, 4096, 3072, 1024);

    for (int b = 0; b < 2; ++b) {
        const size_t qo = (size_t)b * 2048 * 3072;
        vsuf_part_kernel<<<dim3(16, 8), 256, 0, stream>>>(QKVh + qo, QKVl + qo, tsum);
        vsuf_scan_kernel<<<dim3(16), 64, 0, stream>>>(tsum, vsuf);
        attn_kernel<<<dim3(68, 16), 256, 0, stream>>>(
            QKVh + qo, QKVl + qo, vsuf, XAhi, partO, partML, b * 2048);
        attn_combine_kernel<<<dim3(22, 16), 256, 0, stream>>>(
            partO, partML, vsuf, XAhi, b * 2048);
    }

    gemm_pipe_kernel<0><<<dim3(8, 32), 256, 0, stream>>>(
        XAhi, Woh, Wol, b_out, out, nullptr, nullptr, 4096, 1024, 1024);
}

// Round 11
// 182.258 us; speedup vs baseline: 1.5620x; 1.0032x over previous
//
#include <hip/hip_runtime.h>
#include <math.h>

// Problem constants (reference: B=2, S=2048, D=1024, H=16, HD=64)
#define B_ 2
#define S_ 2048
#define D_ 1024
#define H_ 16
#define HD_ 64

typedef unsigned short ushort8 __attribute__((ext_vector_type(8)));
typedef unsigned int u32x4 __attribute__((ext_vector_type(4)));
typedef _Float16 f16x8 __attribute__((ext_vector_type(8)));
typedef _Float16 f16x2 __attribute__((ext_vector_type(2)));
typedef float f32x4 __attribute__((ext_vector_type(4)));

__device__ __forceinline__ unsigned short f2h(float f) {
    union { _Float16 h; unsigned short u; } v;
    v.h = (_Float16)f;                     // native v_cvt_f16_f32, RNE
    return v.u;
}
__device__ __forceinline__ float h2f(unsigned short u) {
    union { unsigned short u; _Float16 h; } v; v.u = u;
    return (float)v.h;
}
// fp16 hi/lo split of 8 fp32 values (residual ~2^-12 relative)
__device__ __forceinline__ void split2x4(f32x4 a, f32x4 b, ushort8& hi, ushort8& lo) {
    #pragma unroll
    for (int i = 0; i < 4; ++i) {
        unsigned short h = f2h(a[i]); hi[i] = h; lo[i] = f2h(a[i] - h2f(h));
    }
    #pragma unroll
    for (int i = 0; i < 4; ++i) {
        unsigned short h = f2h(b[i]); hi[4 + i] = h; lo[4 + i] = f2h(b[i] - h2f(h));
    }
}
__device__ __forceinline__ ushort8 pack2x4h(f32x4 a, f32x4 b) {
    ushort8 hi;
    #pragma unroll
    for (int i = 0; i < 4; ++i) { hi[i] = f2h(a[i]); hi[4 + i] = f2h(b[i]); }
    return hi;
}

// XOR swizzle for [R][64] f16 tiles (128B rows): in-row 16B-chunk permute by row&7.
#define SWZ(row, col) ((((row)) << 6) + (((col)) ^ ((((row)) & 7) << 3)))

__device__ __forceinline__ f32x4 mfma16(f16x8 a, f16x8 b, f32x4 c) {
    return __builtin_amdgcn_mfma_f32_16x16x32_f16(a, b, c, 0, 0, 0);
}

typedef __attribute__((address_space(1))) const void gvoid_t;
typedef __attribute__((address_space(3))) void lvoid_t;
typedef __attribute__((address_space(3))) unsigned short lds_us_t;
__device__ __forceinline__ void gload_lds16(const void* g, void* l) {
    __builtin_amdgcn_global_load_lds((gvoid_t*)g, (lvoid_t*)l, 16, 0, 0);
}
// inline-asm LDS read: opaque to the compiler's waitcnt pass (counted vmcnt survives)
__device__ __forceinline__ f16x8 dsr128(unsigned addr) {
    u32x4 r;
    asm volatile("ds_read_b128 %0, %1" : "=v"(r) : "v"(addr));
    union { u32x4 u; f16x8 h; } cv; cv.u = r; return cv.h;
}

// ---------------------------------------------------------------------------
// conv_rows: fp32 [4096][1024] -> fp16 HI ONLY (A-side of 2-term GEMM),
// pre-swizzled chunks (key = row&7)
// ---------------------------------------------------------------------------
__global__ __launch_bounds__(256) void conv_rows_kernel(
    const float* __restrict__ in, unsigned short* __restrict__ ohi)
{
    const int id = blockIdx.x * 256 + threadIdx.x;   // [0, 4096*128)
    const int r = id >> 7, c = id & 127;
    const float* s = in + (size_t)r * 1024 + c * 8;
    f32x4 v0 = *(const f32x4*)s, v1 = *(const f32x4*)(s + 4);
    ushort8 hi = pack2x4h(v0, v1);
    const int oc = (c & ~7) | ((c ^ r) & 7);
    *(ushort8*)&ohi[(size_t)r * 1024 + oc * 8] = hi;
}

// ---------------------------------------------------------------------------
// conv_wt: W fp32 [1024 k][ldw] -> Wt fp16 h/l [N][1024], transposed +
// pre-swizzled (key = n&7). Grid (K/64, N/64).
// ---------------------------------------------------------------------------
__global__ __launch_bounds__(256) void conv_wt_kernel(
    const float* __restrict__ W, int ldw,
    unsigned short* __restrict__ othi, unsigned short* __restrict__ otlo)
{
    __shared__ float T[64][65];
    const int tid = threadIdx.x;
    const int kx = blockIdx.x * 64, ny = blockIdx.y * 64;
    const int kl = tid >> 2, c0 = (tid & 3) * 16;
    const float* s = W + (size_t)(kx + kl) * ldw + ny + c0;
    #pragma unroll
    for (int i = 0; i < 4; ++i) *(f32x4*)&T[kl][c0 + 4 * i] = *(const f32x4*)(s + 4 * i);
    __syncthreads();
    const int nl = tid >> 2, jj = (tid & 3) * 2;
    #pragma unroll
    for (int p = 0; p < 2; ++p) {
        const int j = jj + p;
        f32x4 a, b;
        #pragma unroll
        for (int i = 0; i < 4; ++i) a[i] = T[j * 8 + i][nl];
        #pragma unroll
        for (int i = 0; i < 4; ++i) b[i] = T[j * 8 + 4 + i][nl];
        ushort8 hi, lo;
        split2x4(a, b, hi, lo);
        const int row = ny + nl;
        const int chunk = blockIdx.x * 8 + (j ^ (nl & 7));
        *(ushort8*)&othi[(size_t)row * 1024 + chunk * 8] = hi;
        *(ushort8*)&otlo[(size_t)row * 1024 + chunk * 8] = lo;
    }
}

// ---------------------------------------------------------------------------
// 2-term fp16 MFMA GEMM: C = Ah @ (Bh + Bl)^T + bias.
// 128x128 tile, BK=32 -> 24KB/tile, 2-buf = 48KB LDS -> 3 blocks/CU.
// Counted vmcnt(6); split lgkmcnt(4). BK=32 swizzle (r11 FIX): 16B chunk
// key = (row&3) ^ ((row>>2)&3) within 64B rows -> every chunk value appears
// exactly 2x among same-parity rows of a 16-row fragment read = 2-way bank
// aliasing (free, m136). r10's key=(row&3) was a 4-way conflict (rows 0,4,
// 8,12 same banks -> 5.3M conflict cycles). Staging composes this key with
// the global row&7 pre-swizzle in the source address; content unchanged.
// A, Bt fp16 globally pre-swizzled. OUTMODE 0: fp32 C. 1: fp16 h/l.
// ---------------------------------------------------------------------------
template<int OUTMODE>
__global__ __launch_bounds__(256, 3) void gemm_pipe_kernel(
    const unsigned short* __restrict__ Ah,
    const unsigned short* __restrict__ Bth, const unsigned short* __restrict__ Btl,
    const float* __restrict__ bias, float* __restrict__ Cf,
    unsigned short* __restrict__ Ohi, unsigned short* __restrict__ Olo,
    int M, int N, int K)
{
    __shared__ __align__(16) unsigned short lds[24576];   // 48KB: 2 x 24KB buffers
    // per buffer: A [0,8192)B, Bh [8192,16384)B, Bl [16384,24576)B; each [128 rows][4 x 16B chunks]

    const int tid = threadIdx.x, lane = tid & 63, w = tid >> 6;
    const int wm = w >> 1, wn = w & 1;
    // XCD-aware bijective swizzle (nwg % 8 == 0 for all grids here)
    const int gx = gridDim.x, nwg = gx * gridDim.y;
    const int lin = blockIdx.y * gx + blockIdx.x;
    const int nl = (lin & 7) * (nwg >> 3) + (lin >> 3);
    const int m0 = (nl / gx) * 128, n0 = (nl % gx) * 128;
    const int col = lane & 15, g = lane >> 4;
    const int NT = K >> 5;

    // staging roles: instr q covers rows (w*2+q)*16 + (lane>>2), chunk = lane&3
    const int sr0 = (w * 2 + 0) * 16 + (lane >> 2);
    const int sr1 = (w * 2 + 1) * 16 + (lane >> 2);
    const int scp = lane & 3;

    auto stage = [&](int tt) {
        unsigned short* dst = &lds[(tt & 1) * 12288];     // shorts
        const int hi8 = (tt >> 1) * 8;
        const int tb4 = (tt & 1) << 2;
        #pragma unroll
        for (int q = 0; q < 2; ++q) {
            const int r = q ? sr1 : sr0;
            // physical global chunk for logical chunk kc = scp ^ (r&3) ^ ((r>>2)&3),
            // composed with the global row&7 pre-swizzle:
            const int p = hi8 + ((tb4 ^ (r & 4)) | (scp ^ ((r >> 2) & 3)));
            const size_t go = (size_t)p * 8;
            const int slotb = (w * 2 + q) * 512;          // shorts (1KB per wave-instr)
            gload_lds16(Ah  + (size_t)(m0 + r) * 1024 + go, dst + 0    + slotb);
            gload_lds16(Bth + (size_t)(n0 + r) * 1024 + go, dst + 4096 + slotb);
            gload_lds16(Btl + (size_t)(n0 + r) * 1024 + go, dst + 8192 + slotb);
        }
    };

    // per-lane ds_read byte addresses: row*64B + ((kchunk ^ key(row))<<4),
    // key(row) = (row&3)^((row>>2)&3) = (col&3)^((col>>2)&3) for fragment rows
    const unsigned ldsb = (unsigned)(size_t)(lds_us_t*)lds;
    const unsigned sk = (unsigned)(((g ^ (col & 3) ^ ((col >> 2) & 3)) & 3) << 4);
    const unsigned aB  = ldsb + (unsigned)((wm * 64 + col) * 64) + sk;
    const unsigned bBh = ldsb + 8192u  + (unsigned)((wn * 64 + col) * 64) + sk;
    const unsigned bBl = ldsb + 16384u + (unsigned)((wn * 64 + col) * 64) + sk;

    f32x4 acc[4][4] = {};

    stage(0);
    stage(1);   // NT >= 2 always

    for (int tt = 0; tt < NT; ++tt) {
        if (tt + 1 < NT) asm volatile("s_waitcnt vmcnt(6)" ::: "memory");
        else             asm volatile("s_waitcnt vmcnt(0)" ::: "memory");
        __builtin_amdgcn_s_barrier();            // buf tt&1 fully published
        __builtin_amdgcn_sched_barrier(0);
        const unsigned bo = (unsigned)((tt & 1) * 24576);   // byte offset

        f16x8 a[4], bh[4], bl[4];
        #pragma unroll
        for (int i = 0; i < 4; ++i) a[i]  = dsr128(aB + bo + i * 1024u);
        #pragma unroll
        for (int i = 0; i < 4; ++i) bh[i] = dsr128(bBh + bo + i * 1024u);
        #pragma unroll
        for (int i = 0; i < 4; ++i) bl[i] = dsr128(bBl + bo + i * 1024u);

        asm volatile("s_waitcnt lgkmcnt(4)" ::: "memory");  // a[] + bh[] done, bl in flight
        __builtin_amdgcn_sched_barrier(0);                   // rule #18
        __builtin_amdgcn_s_setprio(1);
        #pragma unroll
        for (int mi = 0; mi < 4; ++mi)
            #pragma unroll
            for (int nj = 0; nj < 4; ++nj)
                acc[mi][nj] = mfma16(a[mi], bh[nj], acc[mi][nj]);
        asm volatile("s_waitcnt lgkmcnt(0)" ::: "memory");  // bl[] done
        __builtin_amdgcn_sched_barrier(0);
        #pragma unroll
        for (int mi = 0; mi < 4; ++mi)
            #pragma unroll
            for (int nj = 0; nj < 4; ++nj)
                acc[mi][nj] = mfma16(a[mi], bl[nj], acc[mi][nj]);
        __builtin_amdgcn_s_setprio(0);
        __builtin_amdgcn_s_barrier();            // all reads of buf tt&1 done
        __builtin_amdgcn_sched_barrier(0);
        if (tt + 2 < NT) stage(tt + 2);
    }

    // ---- epilogue: per-wave LDS transpose in two 32-row halves (8KB/wave) ----
    __syncthreads();
    float* ow = (float*)((char*)lds + w * 8192);   // [32][64] fp32 per wave
    const int nc = (lane & 7) * 8;
    const int nabs = n0 + wn * 64 + nc;
    f32x4 bi0 = *(const f32x4*)&bias[nabs];
    f32x4 bi1 = *(const f32x4*)&bias[nabs + 4];
    #pragma unroll
    for (int half = 0; half < 2; ++half) {
        __builtin_amdgcn_wave_barrier();
        #pragma unroll
        for (int ml = 0; ml < 2; ++ml)
            #pragma unroll
            for (int nj = 0; nj < 4; ++nj)
                #pragma unroll
                for (int r = 0; r < 4; ++r)
                    ow[(ml * 16 + g * 4 + r) * 64 + nj * 16 + col] = acc[half * 2 + ml][nj][r];
        __builtin_amdgcn_wave_barrier();
        #pragma unroll
        for (int it = 0; it < 4; ++it) {
            const int rl = it * 8 + (lane >> 3);
            f32x4 v0 = *(const f32x4*)&ow[rl * 64 + nc];
            f32x4 v1 = *(const f32x4*)&ow[rl * 64 + nc + 4];
            v0 += bi0; v1 += bi1;
            const int m = m0 + wm * 64 + half * 32 + rl;
            if (OUTMODE == 0) {
                *(f32x4*)&Cf[(size_t)m * N + nabs] = v0;
                *(f32x4*)&Cf[(size_t)m * N + nabs + 4] = v1;
            } else {
                ushort8 hi, lo;
                split2x4(v0, v1, hi, lo);
                const int chunk = (lane & 7) ^ (m & 7);
                const size_t off = (size_t)m * N + n0 + wn * 64 + chunk * 8;
                *(ushort8*)&Ohi[off] = hi;
                *(ushort8*)&Olo[off] = lo;
            }
        }
        __builtin_amdgcn_wave_barrier();
    }
}

// ---------------------------------------------------------------------------
// V suffix tile sums (vectorized): tsum[h][t][d] = sum_{k in tile t} V[k][d]
// ---------------------------------------------------------------------------
__global__ __launch_bounds__(256) void vsuf_part_kernel(
    const unsigned short* __restrict__ qh, const unsigned short* __restrict__ ql,
    float* __restrict__ tsum)
{
    const int h = blockIdx.x, tg = blockIdx.y;    // grid (16, 8)
    const int tl = threadIdx.x >> 6, lane = threadIdx.x & 63;
    const int t = tg * 4 + tl;
    const int dgrp = lane & 7, rr = lane >> 3;
    const int colbase = h * 192 + 128;
    float sacc[8] = {};
    for (int kk = 0; kk < 8; ++kk) {
        const int row = t * 64 + rr + kk * 8;
        const size_t off = (size_t)row * 3072 + colbase + ((dgrp ^ rr) << 3);
        ushort8 vh = *(const ushort8*)&qh[off];
        ushort8 vl = *(const ushort8*)&ql[off];
        #pragma unroll
        for (int e = 0; e < 8; ++e) sacc[e] += h2f(vh[e]) + h2f(vl[e]);
    }
    #pragma unroll
    for (int off = 8; off < 64; off <<= 1)
        #pragma unroll
        for (int e = 0; e < 8; ++e) sacc[e] += __shfl_xor(sacc[e], off);
    if (rr == 0) {
        float* dst = &tsum[((size_t)h * 32 + t) * 64 + dgrp * 8];
        f32x4 v0, v1;
        #pragma unroll
        for (int e = 0; e < 4; ++e) { v0[e] = sacc[e]; v1[e] = sacc[4 + e]; }
        *(f32x4*)dst = v0;
        *(f32x4*)(dst + 4) = v1;
    }
}

__global__ __launch_bounds__(64) void vsuf_scan_kernel(
    const float* __restrict__ tsum, float* __restrict__ vsuf)
{
    const int h = blockIdx.x, d = threadIdx.x;    // 16 blocks x 64 thr
    float acc = 0.f;
    vsuf[((size_t)h * 33 + 32) * 64 + d] = 0.f;
    for (int t = 31; t >= 0; --t) {
        acc += tsum[((size_t)h * 32 + t) * 64 + d];
        vsuf[((size_t)h * 33 + t) * 64 + d] = acc;
    }
}

// ---------------------------------------------------------------------------
// Causal-skip MFMA flash attention with key-range segmentation (r4-r10 proven),
// fp16: QK^T 2-term (Kh·Qh + Kh·Ql), PV 1-term fp16.
// ---------------------------------------------------------------------------
__global__ __launch_bounds__(256, 4) void attn_kernel(
    const unsigned short* __restrict__ qh, const unsigned short* __restrict__ ql,
    const float* __restrict__ vsuf,
    unsigned short* __restrict__ ohi,
    float* __restrict__ partO, float* __restrict__ partML,
    int brow)
{
    __shared__ __align__(16) unsigned short lds[16384];   // 32 KB

    const int tid = threadIdx.x, lane = tid & 63, w = tid >> 6;
    const int g = lane >> 4, oct = g * 8, col = lane & 15;
    const int h = blockIdx.y;
    const int kp = tid & 31, dg = tid >> 5;

    const int job = blockIdx.x;
    int i = job, s = 0, slot = -1;
    if (job >= 10) {
        int r = job - 10, cum = 0;
        for (int ii = 10; ii < 32; ++ii) {
            const int ns = (ii + 10) / 10;
            if (r < cum + ns) { i = ii; s = r - cum; break; }
            cum += ns;
        }
        slot = (size_t)0 + h * 58 + (job - 10);
    }
    const int q0 = i * 64;
    const int ntile_all = i + 1;
    const int t_begin = s * 10;
    const int t_end = (slot < 0) ? ntile_all : min(t_begin + 10, ntile_all);
    const bool isseg = (slot >= 0);

    auto kissue = [&](int ktbase, ushort8* kr) {
        #pragma unroll
        for (int j = 0; j < 2; ++j) {
            const int cc = w * 2 + j;                 // 0..7
            const int row = ktbase + cc * 8 + (lane >> 3);
            kr[j] = *(const ushort8*)(qh + (size_t)row * 3072 + h * 192 + 64 + (lane & 7) * 8);
        }
    };
    auto kwrite = [&](const ushort8* kr) {
        #pragma unroll
        for (int j = 0; j < 2; ++j) {
            const int cc = w * 2 + j;
            *(ushort8*)&lds[cc * 512 + lane * 8] = kr[j];
        }
    };
    auto vload = [&](int ktbase, f16x8& vA, f16x8& vB) {
        const int r0 = ktbase + 2 * kp, r1 = r0 + 1;
        const int pA = dg ^ (r0 & 7), pB = dg ^ (r1 & 7);
        vA = *(const f16x8*)&qh[(size_t)r0 * 3072 + h * 192 + 128 + pA * 8];
        vB = *(const f16x8*)&qh[(size_t)r1 * 3072 + h * 192 + 128 + pB * 8];
    };
    auto vwrite = [&](f16x8 vA, f16x8 vB) {
        #pragma unroll
        for (int e = 0; e < 8; ++e) {
            const int d = dg * 8 + e;
            f16x2 pr; pr[0] = vA[e]; pr[1] = vB[e];
            *(f16x2*)&lds[8192 + SWZ(d, 2 * kp)] = pr;
        }
    };

    // ---- stage Q tile (h and l; pre-swizzled global -> linear LDS) ----
    #pragma unroll
    for (int j = 0; j < 4; ++j) {
        const int cc = w * 4 + j;
        const unsigned short* src = (cc < 8) ? qh : ql;
        const int c7 = cc & 7;
        const int row = q0 + c7 * 8 + (lane >> 3);
        gload_lds16(src + (size_t)row * 3072 + h * 192 + (lane & 7) * 8,
                    &lds[(cc < 8 ? 0 : 4096) + c7 * 512]);
    }
    ushort8 kr[2]; f16x8 vA, vB;
    kissue(t_begin * 64, kr);
    vload(t_begin * 64, vA, vB);
    __syncthreads();
    f16x8 qfh[2], qfl[2];
    {
        const int qrow = w * 16 + col;
        qfh[0] = *(const f16x8*)&lds[SWZ(qrow, oct)];
        qfh[1] = *(const f16x8*)&lds[SWZ(qrow, 32 + oct)];
        qfl[0] = *(const f16x8*)&lds[4096 + SWZ(qrow, oct)];
        qfl[1] = *(const f16x8*)&lds[4096 + SWZ(qrow, 32 + oct)];
    }
    __syncthreads();
    kwrite(kr);
    vwrite(vA, vB);
    __syncthreads();

    const int qg = q0 + w * 16 + col;
    float m_run = isseg ? -INFINITY : 0.f;
    float l_run = 0.f;
    f32x4 oacc[4] = {};

    for (int t = t_begin; t < t_end; ++t) {
        const int kt = t * 64;
        const bool pf = (t + 1 < t_end);
        if (pf) { kissue(kt + 64, kr); vload(kt + 64, vA, vB); }

        // ---- scores: S^T[key][q] = K·Q (2-term fp16) ----
        f32x4 sacc[4] = {};
        #pragma unroll
        for (int c = 0; c < 2; ++c)
            #pragma unroll
            for (int t4 = 0; t4 < 4; ++t4) {
                const int krow = t4 * 16 + col;
                f16x8 khf = *(const f16x8*)&lds[SWZ(krow, c * 32 + oct)];
                sacc[t4] = mfma16(khf, qfh[c], sacc[t4]);
                sacc[t4] = mfma16(khf, qfl[c], sacc[t4]);
            }

        float p[16];
        float mx = -INFINITY;
        if (t == ntile_all - 1) {
            #pragma unroll
            for (int t4 = 0; t4 < 4; ++t4)
                #pragma unroll
                for (int r = 0; r < 4; ++r) {
                    float sv = sacc[t4][r] * 0.125f;
                    if (kt + t4 * 16 + g * 4 + r > qg) sv = 0.0f;
                    p[t4 * 4 + r] = sv; mx = fmaxf(mx, sv);
                }
        } else {
            #pragma unroll
            for (int t4 = 0; t4 < 4; ++t4)
                #pragma unroll
                for (int r = 0; r < 4; ++r) {
                    float sv = sacc[t4][r] * 0.125f;
                    p[t4 * 4 + r] = sv; mx = fmaxf(mx, sv);
                }
        }
        mx = fmaxf(mx, __shfl_xor(mx, 16));
        mx = fmaxf(mx, __shfl_xor(mx, 32));
        const float mnew = fmaxf(m_run, mx);
        const float corr = __expf(m_run - mnew);
        float ls = 0.f;
        unsigned short* Pw = &lds[12288 + w * 1024];
        #pragma unroll
        for (int t4 = 0; t4 < 4; ++t4)
            #pragma unroll
            for (int rp = 0; rp < 2; ++rp) {
                float e0 = __expf(p[t4 * 4 + rp * 2] - mnew);
                float e1 = __expf(p[t4 * 4 + rp * 2 + 1] - mnew);
                ls += e0 + e1;
                f16x2 pk; pk[0] = (_Float16)e0; pk[1] = (_Float16)e1;
                *(f16x2*)&Pw[SWZ(col, t4 * 16 + g * 4 + rp * 2)] = pk;
            }
        ls += __shfl_xor(ls, 16);
        ls += __shfl_xor(ls, 32);
        l_run = l_run * corr + ls;
        m_run = mnew;

        __builtin_amdgcn_wave_barrier();

        __syncthreads();                 // (A)
        if (pf) kwrite(kr);

        #pragma unroll
        for (int dt = 0; dt < 4; ++dt) {
            oacc[dt][0] *= corr; oacc[dt][1] *= corr;
            oacc[dt][2] *= corr; oacc[dt][3] *= corr;
        }
        #pragma unroll
        for (int c = 0; c < 2; ++c) {
            f16x8 pfv = *(const f16x8*)&Pw[SWZ(col, c * 32 + oct)];
            #pragma unroll
            for (int dt = 0; dt < 4; ++dt) {
                f16x8 vh = *(const f16x8*)&lds[8192 + SWZ(dt * 16 + col, c * 32 + oct)];
                oacc[dt] = mfma16(vh, pfv, oacc[dt]);
            }
        }

        __syncthreads();                 // (B)
        if (pf) vwrite(vA, vB);
    }

    if (isseg) {
        float* po = partO + (size_t)slot * 4096;
        #pragma unroll
        for (int dt = 0; dt < 4; ++dt)
            #pragma unroll
            for (int r = 0; r < 4; ++r)
                po[(dt * 16 + g * 4 + r) * 64 + w * 16 + col] = oacc[dt][r];
        if (g == 0) {
            partML[(size_t)slot * 128 + w * 16 + col] = m_run;
            partML[(size_t)slot * 128 + 64 + w * 16 + col] = l_run;
        }
        return;
    }

    {
        const float wt = __expf(-m_run);
        l_run += (float)(S_ - q0 - 64) * wt;
        const float* vs = vsuf + ((size_t)h * 33 + (i + 1)) * 64;
        #pragma unroll
        for (int dt = 0; dt < 4; ++dt)
            #pragma unroll
            for (int r = 0; r < 4; ++r)
                oacc[dt][r] += wt * vs[dt * 16 + g * 4 + r];
    }
    const float inv = 1.f / l_run;
    float* ow = (float*)&lds[w * 4096];
    const int q = lane >> 2, jj = lane & 3;
    #pragma unroll
    for (int half = 0; half < 2; ++half) {
        __builtin_amdgcn_wave_barrier();
        #pragma unroll
        for (int t4 = 0; t4 < 2; ++t4)
            #pragma unroll
            for (int r = 0; r < 4; ++r)
                ow[col * 40 + t4 * 16 + g * 4 + r] = oacc[half * 2 + t4][r] * inv;
        __builtin_amdgcn_wave_barrier();
        f32x4 v0 = *(const f32x4*)&ow[q * 40 + jj * 8];
        f32x4 v1 = *(const f32x4*)&ow[q * 40 + jj * 8 + 4];
        ushort8 hi = pack2x4h(v0, v1);
        const int m = brow + q0 + w * 16 + q;
        const int chunk = (half * 4 + jj) ^ (m & 7);
        *(ushort8*)&ohi[(size_t)m * 1024 + h * 64 + chunk * 8] = hi;
    }
}

// ---------------------------------------------------------------------------
// Combine partials for split q-tiles (i>=10). (r4-r10 proven; fp16 hi output)
// ---------------------------------------------------------------------------
__global__ __launch_bounds__(256) void attn_combine_kernel(
    const float* __restrict__ partO, const float* __restrict__ partML,
    const float* __restrict__ vsuf,
    unsigned short* __restrict__ ohi,
    int brow)
{
    const int i = 10 + blockIdx.x;
    const int h = blockIdx.y;
    const int nseg = (i + 10) / 10;
    int cum = 0;
    for (int j = 10; j < i; ++j) cum += (j + 10) / 10;
    const int slot0 = h * 58 + cum;
    const int q = threadIdx.x & 63, dgrp = threadIdx.x >> 6;
    const int q0 = i * 64;

    float mstar = 0.f;
    for (int sg = 0; sg < nseg; ++sg)
        mstar = fmaxf(mstar, partML[(size_t)(slot0 + sg) * 128 + q]);
    const float wtail = __expf(-mstar);
    float lstar = (float)(S_ - q0 - 64) * wtail;

    float od[16];
    const float* vs = vsuf + ((size_t)h * 33 + i + 1) * 64 + dgrp * 16;
    #pragma unroll
    for (int k = 0; k < 16; ++k) od[k] = wtail * vs[k];

    for (int sg = 0; sg < nseg; ++sg) {
        const float ms = partML[(size_t)(slot0 + sg) * 128 + q];
        const float lsv = partML[(size_t)(slot0 + sg) * 128 + 64 + q];
        const float wv = __expf(ms - mstar);
        lstar += lsv * wv;
        const float* po = partO + (size_t)(slot0 + sg) * 4096 + (size_t)(dgrp * 16) * 64 + q;
        #pragma unroll
        for (int k = 0; k < 16; ++k) od[k] += wv * po[k * 64];
    }

    const float inv = 1.f / lstar;
    f32x4 a0, a1, b0, b1;
    #pragma unroll
    for (int k = 0; k < 4; ++k) {
        a0[k] = od[k] * inv; a1[k] = od[4 + k] * inv;
        b0[k] = od[8 + k] * inv; b1[k] = od[12 + k] * inv;
    }
    ushort8 hi0 = pack2x4h(a0, a1);
    ushort8 hi1 = pack2x4h(b0, b1);
    const int mrow = brow + q0 + q;
    const int c0 = (dgrp * 2) ^ (mrow & 7);
    const int c1 = (dgrp * 2 + 1) ^ (mrow & 7);
    const size_t base = (size_t)mrow * 1024 + h * 64;
    *(ushort8*)&ohi[base + c0 * 8] = hi0;
    *(ushort8*)&ohi[base + c1 * 8] = hi1;
}

// ---------------------------------------------------------------------------
extern "C" void kernel_launch(void* const* d_in, const int* in_sizes, int n_in,
                              void* d_out, int out_size, void* d_ws, size_t ws_size,
                              hipStream_t stream) {
    const float* x     = (const float*)d_in[0];   // [B,S,D]
    const float* W_qkv = (const float*)d_in[1];   // [D,3D]
    const float* b_qkv = (const float*)d_in[2];   // [3D]
    const float* W_out = (const float*)d_in[3];   // [D,D]
    const float* b_out = (const float*)d_in[4];   // [D]
    float* out = (float*)d_out;                   // [B,S,D]

    // ws layout (~76 MB; proven available in r8-r10)
    unsigned short* us  = (unsigned short*)d_ws;
    unsigned short* Wqh = us;                                  // [3072][1024]
    unsigned short* Wql = Wqh + (size_t)3072 * 1024;
    unsigned short* Woh = Wql + (size_t)3072 * 1024;           // [1024][1024]
    unsigned short* Wol = Woh + (size_t)1024 * 1024;
    unsigned short* XAhi = Wol + (size_t)1024 * 1024;          // [4096][1024] X, then attn-out (hi only)
    unsigned short* QKVh = XAhi + (size_t)4096 * 1024;         // [4096][3072]
    unsigned short* QKVl = QKVh + (size_t)4096 * 3072;
    float* tsum = (float*)(QKVl + (size_t)4096 * 3072);        // [16][32][64]
    float* vsuf = tsum + (size_t)16 * 32 * 64;                 // [16][33][64]

    float* partO  = out;                                       // [928][4096] scratch in d_out
    float* partML = out + (size_t)928 * 4096;                  // [928][128]

    conv_wt_kernel<<<dim3(16, 48), 256, 0, stream>>>(W_qkv, 3072, Wqh, Wql);
    conv_wt_kernel<<<dim3(16, 16), 256, 0, stream>>>(W_out, 1024, Woh, Wol);
    conv_rows_kernel<<<dim3(2048), 256, 0, stream>>>(x, XAhi);

    // fused-batch QKV projection (both batches, M = 4096): grid 768 = 3 blocks/CU
    gemm_pipe_kernel<1><<<dim3(24, 32), 256, 0, stream>>>(
        XAhi, Wqh, Wql, b_qkv, nullptr, QKVh, QKVl, 4096, 3072, 1024);

    for (int b = 0; b < 2; ++b) {
        const size_t qo = (size_t)b * 2048 * 3072;
        vsuf_part_kernel<<<dim3(16, 8), 256, 0, stream>>>(QKVh + qo, QKVl + qo, tsum);
        vsuf_scan_kernel<<<dim3(16), 64, 0, stream>>>(tsum, vsuf);
        attn_kernel<<<dim3(68, 16), 256, 0, stream>>>(
            QKVh + qo, QKVl + qo, vsuf, XAhi, partO, partML, b * 2048);
        attn_combine_kernel<<<dim3(22, 16), 256, 0, stream>>>(
            partO, partML, vsuf, XAhi, b * 2048);
    }

    gemm_pipe_kernel<0><<<dim3(8, 32), 256, 0, stream>>>(
        XAhi, Woh, Wol, b_out, out, nullptr, nullptr, 4096, 1024, 1024);
}

// Round 12
// 175.468 us; speedup vs baseline: 1.6225x; 1.0387x over previous
//
#include <hip/hip_runtime.h>
#include <math.h>

// Problem constants (reference: B=2, S=2048, D=1024, H=16, HD=64)
#define B_ 2
#define S_ 2048
#define D_ 1024
#define H_ 16
#define HD_ 64

typedef unsigned short ushort8 __attribute__((ext_vector_type(8)));
typedef unsigned int u32x4 __attribute__((ext_vector_type(4)));
typedef _Float16 f16x8 __attribute__((ext_vector_type(8)));
typedef _Float16 f16x2 __attribute__((ext_vector_type(2)));
typedef float f32x4 __attribute__((ext_vector_type(4)));

__device__ __forceinline__ unsigned short f2h(float f) {
    union { _Float16 h; unsigned short u; } v;
    v.h = (_Float16)f;                     // native v_cvt_f16_f32, RNE
    return v.u;
}
__device__ __forceinline__ float h2f(unsigned short u) {
    union { unsigned short u; _Float16 h; } v; v.u = u;
    return (float)v.h;
}
// fp16 hi/lo split of 8 fp32 values (residual ~2^-12 relative)
__device__ __forceinline__ void split2x4(f32x4 a, f32x4 b, ushort8& hi, ushort8& lo) {
    #pragma unroll
    for (int i = 0; i < 4; ++i) {
        unsigned short h = f2h(a[i]); hi[i] = h; lo[i] = f2h(a[i] - h2f(h));
    }
    #pragma unroll
    for (int i = 0; i < 4; ++i) {
        unsigned short h = f2h(b[i]); hi[4 + i] = h; lo[4 + i] = f2h(b[i] - h2f(h));
    }
}
__device__ __forceinline__ ushort8 pack2x4h(f32x4 a, f32x4 b) {
    ushort8 hi;
    #pragma unroll
    for (int i = 0; i < 4; ++i) { hi[i] = f2h(a[i]); hi[4 + i] = f2h(b[i]); }
    return hi;
}

// XOR swizzle for [R][64] f16 tiles (128B rows): in-row 16B-chunk permute by row&7.
#define SWZ(row, col) ((((row)) << 6) + (((col)) ^ ((((row)) & 7) << 3)))

__device__ __forceinline__ f32x4 mfma16(f16x8 a, f16x8 b, f32x4 c) {
    return __builtin_amdgcn_mfma_f32_16x16x32_f16(a, b, c, 0, 0, 0);
}

typedef __attribute__((address_space(1))) const void gvoid_t;
typedef __attribute__((address_space(3))) void lvoid_t;
typedef __attribute__((address_space(3))) unsigned short lds_us_t;
__device__ __forceinline__ void gload_lds16(const void* g, void* l) {
    __builtin_amdgcn_global_load_lds((gvoid_t*)g, (lvoid_t*)l, 16, 0, 0);
}
// inline-asm LDS read: opaque to the compiler's waitcnt pass (counted vmcnt survives)
__device__ __forceinline__ f16x8 dsr128(unsigned addr) {
    u32x4 r;
    asm volatile("ds_read_b128 %0, %1" : "=v"(r) : "v"(addr));
    union { u32x4 u; f16x8 h; } cv; cv.u = r; return cv.h;
}

// ---------------------------------------------------------------------------
// conv_rows: fp32 [4096][1024] -> fp16 HI ONLY, pre-swizzled (key = row&7)
// ---------------------------------------------------------------------------
__global__ __launch_bounds__(256) void conv_rows_kernel(
    const float* __restrict__ in, unsigned short* __restrict__ ohi)
{
    const int id = blockIdx.x * 256 + threadIdx.x;   // [0, 4096*128)
    const int r = id >> 7, c = id & 127;
    const float* s = in + (size_t)r * 1024 + c * 8;
    f32x4 v0 = *(const f32x4*)s, v1 = *(const f32x4*)(s + 4);
    ushort8 hi = pack2x4h(v0, v1);
    const int oc = (c & ~7) | ((c ^ r) & 7);
    *(ushort8*)&ohi[(size_t)r * 1024 + oc * 8] = hi;
}

// ---------------------------------------------------------------------------
// conv_wt: W fp32 [1024 k][ldw] -> Wt fp16 h/l [N][1024], transposed +
// pre-swizzled (key = n&7). Grid (K/64, N/64).
// ---------------------------------------------------------------------------
__global__ __launch_bounds__(256) void conv_wt_kernel(
    const float* __restrict__ W, int ldw,
    unsigned short* __restrict__ othi, unsigned short* __restrict__ otlo)
{
    __shared__ float T[64][65];
    const int tid = threadIdx.x;
    const int kx = blockIdx.x * 64, ny = blockIdx.y * 64;
    const int kl = tid >> 2, c0 = (tid & 3) * 16;
    const float* s = W + (size_t)(kx + kl) * ldw + ny + c0;
    #pragma unroll
    for (int i = 0; i < 4; ++i) *(f32x4*)&T[kl][c0 + 4 * i] = *(const f32x4*)(s + 4 * i);
    __syncthreads();
    const int nl = tid >> 2, jj = (tid & 3) * 2;
    #pragma unroll
    for (int p = 0; p < 2; ++p) {
        const int j = jj + p;
        f32x4 a, b;
        #pragma unroll
        for (int i = 0; i < 4; ++i) a[i] = T[j * 8 + i][nl];
        #pragma unroll
        for (int i = 0; i < 4; ++i) b[i] = T[j * 8 + 4 + i][nl];
        ushort8 hi, lo;
        split2x4(a, b, hi, lo);
        const int row = ny + nl;
        const int chunk = blockIdx.x * 8 + (j ^ (nl & 7));
        *(ushort8*)&othi[(size_t)row * 1024 + chunk * 8] = hi;
        *(ushort8*)&otlo[(size_t)row * 1024 + chunk * 8] = lo;
    }
}

// ---------------------------------------------------------------------------
// 2-term fp16 MFMA GEMM (r10/r11 proven): C = Ah @ (Bh + Bl)^T (+ bias).
// 128x128 tile, BK=32, 48KB LDS dbuf, 3 blocks/CU, counted vmcnt(6).
// OUTMODE 1: fp16 h/l pre-swizzled out (+bias).
// OUTMODE 2: SPLIT-K fp32 out. grid.y doubled; lower half = K[0,512)+bias->Cf,
//            upper half = K[512,1024) raw -> Cf1. Row stride fixed 1024.
// ---------------------------------------------------------------------------
template<int OUTMODE>
__global__ __launch_bounds__(256, 3) void gemm_pipe_kernel(
    const unsigned short* __restrict__ Ah,
    const unsigned short* __restrict__ Bth, const unsigned short* __restrict__ Btl,
    const float* __restrict__ bias, float* __restrict__ Cf, float* __restrict__ Cf1,
    unsigned short* __restrict__ Ohi, unsigned short* __restrict__ Olo,
    int M, int N, int K)
{
    __shared__ __align__(16) unsigned short lds[24576];   // 48KB: 2 x 24KB buffers

    const int tid = threadIdx.x, lane = tid & 63, w = tid >> 6;
    const int wm = w >> 1, wn = w & 1;
    // XCD-aware bijective swizzle (nwg % 8 == 0 for all grids here)
    const int gx = gridDim.x, nwg = gx * gridDim.y;
    const int lin = blockIdx.y * gx + blockIdx.x;
    const int nl = (lin & 7) * (nwg >> 3) + (lin >> 3);
    int mblk = nl / gx;
    int koff = 0;
    float* Cfw = Cf;
    bool dobias = (OUTMODE != 2);
    if (OUTMODE == 2) {
        const int halfrows = (int)(gridDim.y >> 1);
        if (mblk >= halfrows) { mblk -= halfrows; koff = 512; Cfw = Cf1; }
        else dobias = true;
    }
    const int m0 = mblk * 128, n0 = (nl % gx) * 128;
    const int col = lane & 15, g = lane >> 4;
    const int NT = K >> 5;

    const int sr0 = (w * 2 + 0) * 16 + (lane >> 2);
    const int sr1 = (w * 2 + 1) * 16 + (lane >> 2);
    const int scp = lane & 3;

    auto stage = [&](int tt) {
        unsigned short* dst = &lds[(tt & 1) * 12288];
        const int hi8 = (tt >> 1) * 8;
        const int tb4 = (tt & 1) << 2;
        #pragma unroll
        for (int q = 0; q < 2; ++q) {
            const int r = q ? sr1 : sr0;
            const int p = hi8 + ((tb4 ^ (r & 4)) | (scp ^ ((r >> 2) & 3)));
            const size_t go = (size_t)p * 8 + koff;
            const int slotb = (w * 2 + q) * 512;
            gload_lds16(Ah  + (size_t)(m0 + r) * 1024 + go, dst + 0    + slotb);
            gload_lds16(Bth + (size_t)(n0 + r) * 1024 + go, dst + 4096 + slotb);
            gload_lds16(Btl + (size_t)(n0 + r) * 1024 + go, dst + 8192 + slotb);
        }
    };

    const unsigned ldsb = (unsigned)(size_t)(lds_us_t*)lds;
    const unsigned sk = (unsigned)(((g ^ (col & 3) ^ ((col >> 2) & 3)) & 3) << 4);
    const unsigned aB  = ldsb + (unsigned)((wm * 64 + col) * 64) + sk;
    const unsigned bBh = ldsb + 8192u  + (unsigned)((wn * 64 + col) * 64) + sk;
    const unsigned bBl = ldsb + 16384u + (unsigned)((wn * 64 + col) * 64) + sk;

    f32x4 acc[4][4] = {};

    stage(0);
    stage(1);

    for (int tt = 0; tt < NT; ++tt) {
        if (tt + 1 < NT) asm volatile("s_waitcnt vmcnt(6)" ::: "memory");
        else             asm volatile("s_waitcnt vmcnt(0)" ::: "memory");
        __builtin_amdgcn_s_barrier();
        __builtin_amdgcn_sched_barrier(0);
        const unsigned bo = (unsigned)((tt & 1) * 24576);

        f16x8 a[4], bh[4], bl[4];
        #pragma unroll
        for (int i = 0; i < 4; ++i) a[i]  = dsr128(aB + bo + i * 1024u);
        #pragma unroll
        for (int i = 0; i < 4; ++i) bh[i] = dsr128(bBh + bo + i * 1024u);
        #pragma unroll
        for (int i = 0; i < 4; ++i) bl[i] = dsr128(bBl + bo + i * 1024u);

        asm volatile("s_waitcnt lgkmcnt(4)" ::: "memory");
        __builtin_amdgcn_sched_barrier(0);
        __builtin_amdgcn_s_setprio(1);
        #pragma unroll
        for (int mi = 0; mi < 4; ++mi)
            #pragma unroll
            for (int nj = 0; nj < 4; ++nj)
                acc[mi][nj] = mfma16(a[mi], bh[nj], acc[mi][nj]);
        asm volatile("s_waitcnt lgkmcnt(0)" ::: "memory");
        __builtin_amdgcn_sched_barrier(0);
        #pragma unroll
        for (int mi = 0; mi < 4; ++mi)
            #pragma unroll
            for (int nj = 0; nj < 4; ++nj)
                acc[mi][nj] = mfma16(a[mi], bl[nj], acc[mi][nj]);
        __builtin_amdgcn_s_setprio(0);
        __builtin_amdgcn_s_barrier();
        __builtin_amdgcn_sched_barrier(0);
        if (tt + 2 < NT) stage(tt + 2);
    }

    // ---- epilogue: per-wave LDS transpose in two 32-row halves ----
    __syncthreads();
    float* ow = (float*)((char*)lds + w * 8192);   // [32][64] fp32 per wave
    const int nc = (lane & 7) * 8;
    const int nabs = n0 + wn * 64 + nc;
    f32x4 bi0 = {}, bi1 = {};
    if (dobias) { bi0 = *(const f32x4*)&bias[nabs]; bi1 = *(const f32x4*)&bias[nabs + 4]; }
    #pragma unroll
    for (int half = 0; half < 2; ++half) {
        __builtin_amdgcn_wave_barrier();
        #pragma unroll
        for (int ml = 0; ml < 2; ++ml)
            #pragma unroll
            for (int nj = 0; nj < 4; ++nj)
                #pragma unroll
                for (int r = 0; r < 4; ++r)
                    ow[(ml * 16 + g * 4 + r) * 64 + nj * 16 + col] = acc[half * 2 + ml][nj][r];
        __builtin_amdgcn_wave_barrier();
        #pragma unroll
        for (int it = 0; it < 4; ++it) {
            const int rl = it * 8 + (lane >> 3);
            f32x4 v0 = *(const f32x4*)&ow[rl * 64 + nc];
            f32x4 v1 = *(const f32x4*)&ow[rl * 64 + nc + 4];
            if (dobias) { v0 += bi0; v1 += bi1; }
            const int m = m0 + wm * 64 + half * 32 + rl;
            if (OUTMODE == 1) {
                ushort8 hi, lo;
                split2x4(v0, v1, hi, lo);
                const int chunk = (lane & 7) ^ (m & 7);
                const size_t off = (size_t)m * N + n0 + wn * 64 + chunk * 8;
                *(ushort8*)&Ohi[off] = hi;
                *(ushort8*)&Olo[off] = lo;
            } else {
                *(f32x4*)&Cfw[(size_t)m * N + nabs] = v0;
                *(f32x4*)&Cfw[(size_t)m * N + nabs + 4] = v1;
            }
        }
        __builtin_amdgcn_wave_barrier();
    }
}

// ---------------------------------------------------------------------------
// out += p1   (split-K combine; out already holds half0 + bias)
// ---------------------------------------------------------------------------
__global__ __launch_bounds__(256) void addp_kernel(
    float* __restrict__ out, const float* __restrict__ p1)
{
    const size_t idx = ((size_t)blockIdx.x * 256 + threadIdx.x) * 4;
    f32x4 v = *(const f32x4*)&out[idx];
    f32x4 u = *(const f32x4*)&p1[idx];
    v += u;
    *(f32x4*)&out[idx] = v;
}

// ---------------------------------------------------------------------------
// V suffix tile sums, batched: grid (32, 8); blockIdx.x = b*16+h
// ---------------------------------------------------------------------------
__global__ __launch_bounds__(256) void vsuf_part_kernel(
    const unsigned short* __restrict__ qh, const unsigned short* __restrict__ ql,
    float* __restrict__ tsum)
{
    const int bh = blockIdx.x, tg = blockIdx.y;
    const int b = bh >> 4, h = bh & 15;
    const unsigned short* qhB = qh + (size_t)b * 2048 * 3072;
    const unsigned short* qlB = ql + (size_t)b * 2048 * 3072;
    const int tl = threadIdx.x >> 6, lane = threadIdx.x & 63;
    const int t = tg * 4 + tl;
    const int dgrp = lane & 7, rr = lane >> 3;
    const int colbase = h * 192 + 128;
    float sacc[8] = {};
    for (int kk = 0; kk < 8; ++kk) {
        const int row = t * 64 + rr + kk * 8;
        const size_t off = (size_t)row * 3072 + colbase + ((dgrp ^ rr) << 3);
        ushort8 vh = *(const ushort8*)&qhB[off];
        ushort8 vl = *(const ushort8*)&qlB[off];
        #pragma unroll
        for (int e = 0; e < 8; ++e) sacc[e] += h2f(vh[e]) + h2f(vl[e]);
    }
    #pragma unroll
    for (int off = 8; off < 64; off <<= 1)
        #pragma unroll
        for (int e = 0; e < 8; ++e) sacc[e] += __shfl_xor(sacc[e], off);
    if (rr == 0) {
        float* dst = &tsum[((size_t)bh * 32 + t) * 64 + dgrp * 8];
        f32x4 v0, v1;
        #pragma unroll
        for (int e = 0; e < 4; ++e) { v0[e] = sacc[e]; v1[e] = sacc[4 + e]; }
        *(f32x4*)dst = v0;
        *(f32x4*)(dst + 4) = v1;
    }
}

__global__ __launch_bounds__(64) void vsuf_scan_kernel(
    const float* __restrict__ tsum, float* __restrict__ vsuf)
{
    const int bh = blockIdx.x, d = threadIdx.x;   // 32 blocks x 64 thr
    float acc = 0.f;
    vsuf[((size_t)bh * 33 + 32) * 64 + d] = 0.f;
    for (int t = 31; t >= 0; --t) {
        acc += tsum[((size_t)bh * 32 + t) * 64 + d];
        vsuf[((size_t)bh * 33 + t) * 64 + d] = acc;
    }
}

// ---------------------------------------------------------------------------
// Causal-skip MFMA flash attention, BATCH-FUSED, SEGLEN=16.
// grid (48, 32): blockIdx.y = b*16+h. jobs: 0..15 direct q-tile i=15-job
// (longest first); 16..47: r=job-16, i=16+(r>>1), seg s=r&1 (16 K-tiles max).
// Seg partials (fp32 O^T,m,l) -> partO slot ((b*16+h)*32 + r) in d_out.
// fp16: QK^T 2-term, PV 1-term. (structure r4-r11 proven)
// ---------------------------------------------------------------------------
__global__ __launch_bounds__(256, 4) void attn_kernel(
    const unsigned short* __restrict__ qh, const unsigned short* __restrict__ ql,
    const float* __restrict__ vsuf,
    unsigned short* __restrict__ ohi,
    float* __restrict__ partO, float* __restrict__ partML)
{
    __shared__ __align__(16) unsigned short lds[16384];   // 32 KB

    const int tid = threadIdx.x, lane = tid & 63, w = tid >> 6;
    const int g = lane >> 4, oct = g * 8, col = lane & 15;
    const int bh = blockIdx.y;
    const int b = bh >> 4, h = bh & 15;
    const unsigned short* qhB = qh + (size_t)b * 2048 * 3072;
    const unsigned short* qlB = ql + (size_t)b * 2048 * 3072;
    const float* vsufB = vsuf + (size_t)bh * 33 * 64;
    const int brow = b * 2048;
    const int kp = tid & 31, dg = tid >> 5;

    const int job = blockIdx.x;
    int i, s = 0, slot = -1;
    if (job < 16) { i = 15 - job; }
    else { const int r = job - 16; i = 16 + (r >> 1); s = r & 1; slot = (bh << 5) + r; }
    const int q0 = i * 64;
    const int ntile_all = i + 1;
    const int t_begin = s * 16;
    const int t_end = (slot < 0) ? ntile_all : min(t_begin + 16, ntile_all);
    const bool isseg = (slot >= 0);

    auto kissue = [&](int ktbase, ushort8* kr) {
        #pragma unroll
        for (int j = 0; j < 2; ++j) {
            const int cc = w * 2 + j;
            const int row = ktbase + cc * 8 + (lane >> 3);
            kr[j] = *(const ushort8*)(qhB + (size_t)row * 3072 + h * 192 + 64 + (lane & 7) * 8);
        }
    };
    auto kwrite = [&](const ushort8* kr) {
        #pragma unroll
        for (int j = 0; j < 2; ++j) {
            const int cc = w * 2 + j;
            *(ushort8*)&lds[cc * 512 + lane * 8] = kr[j];
        }
    };
    auto vload = [&](int ktbase, f16x8& vA, f16x8& vB) {
        const int r0 = ktbase + 2 * kp, r1 = r0 + 1;
        const int pA = dg ^ (r0 & 7), pB = dg ^ (r1 & 7);
        vA = *(const f16x8*)&qhB[(size_t)r0 * 3072 + h * 192 + 128 + pA * 8];
        vB = *(const f16x8*)&qhB[(size_t)r1 * 3072 + h * 192 + 128 + pB * 8];
    };
    auto vwrite = [&](f16x8 vA, f16x8 vB) {
        #pragma unroll
        for (int e = 0; e < 8; ++e) {
            const int d = dg * 8 + e;
            f16x2 pr; pr[0] = vA[e]; pr[1] = vB[e];
            *(f16x2*)&lds[8192 + SWZ(d, 2 * kp)] = pr;
        }
    };

    // ---- stage Q tile (h and l; pre-swizzled global -> linear LDS) ----
    #pragma unroll
    for (int j = 0; j < 4; ++j) {
        const int cc = w * 4 + j;
        const unsigned short* src = (cc < 8) ? qhB : qlB;
        const int c7 = cc & 7;
        const int row = q0 + c7 * 8 + (lane >> 3);
        gload_lds16(src + (size_t)row * 3072 + h * 192 + (lane & 7) * 8,
                    &lds[(cc < 8 ? 0 : 4096) + c7 * 512]);
    }
    ushort8 kr[2]; f16x8 vA, vB;
    kissue(t_begin * 64, kr);
    vload(t_begin * 64, vA, vB);
    __syncthreads();
    f16x8 qfh[2], qfl[2];
    {
        const int qrow = w * 16 + col;
        qfh[0] = *(const f16x8*)&lds[SWZ(qrow, oct)];
        qfh[1] = *(const f16x8*)&lds[SWZ(qrow, 32 + oct)];
        qfl[0] = *(const f16x8*)&lds[4096 + SWZ(qrow, oct)];
        qfl[1] = *(const f16x8*)&lds[4096 + SWZ(qrow, 32 + oct)];
    }
    __syncthreads();
    kwrite(kr);
    vwrite(vA, vB);
    __syncthreads();

    const int qg = q0 + w * 16 + col;
    float m_run = isseg ? -INFINITY : 0.f;
    float l_run = 0.f;
    f32x4 oacc[4] = {};

    for (int t = t_begin; t < t_end; ++t) {
        const int kt = t * 64;
        const bool pf = (t + 1 < t_end);
        if (pf) { kissue(kt + 64, kr); vload(kt + 64, vA, vB); }

        // ---- scores: S^T[key][q] = K·Q (2-term fp16) ----
        f32x4 sacc[4] = {};
        #pragma unroll
        for (int c = 0; c < 2; ++c)
            #pragma unroll
            for (int t4 = 0; t4 < 4; ++t4) {
                const int krow = t4 * 16 + col;
                f16x8 khf = *(const f16x8*)&lds[SWZ(krow, c * 32 + oct)];
                sacc[t4] = mfma16(khf, qfh[c], sacc[t4]);
                sacc[t4] = mfma16(khf, qfl[c], sacc[t4]);
            }

        float p[16];
        float mx = -INFINITY;
        if (t == ntile_all - 1) {
            #pragma unroll
            for (int t4 = 0; t4 < 4; ++t4)
                #pragma unroll
                for (int r = 0; r < 4; ++r) {
                    float sv = sacc[t4][r] * 0.125f;
                    if (kt + t4 * 16 + g * 4 + r > qg) sv = 0.0f;
                    p[t4 * 4 + r] = sv; mx = fmaxf(mx, sv);
                }
        } else {
            #pragma unroll
            for (int t4 = 0; t4 < 4; ++t4)
                #pragma unroll
                for (int r = 0; r < 4; ++r) {
                    float sv = sacc[t4][r] * 0.125f;
                    p[t4 * 4 + r] = sv; mx = fmaxf(mx, sv);
                }
        }
        mx = fmaxf(mx, __shfl_xor(mx, 16));
        mx = fmaxf(mx, __shfl_xor(mx, 32));
        const float mnew = fmaxf(m_run, mx);
        const float corr = __expf(m_run - mnew);
        float ls = 0.f;
        unsigned short* Pw = &lds[12288 + w * 1024];
        #pragma unroll
        for (int t4 = 0; t4 < 4; ++t4)
            #pragma unroll
            for (int rp = 0; rp < 2; ++rp) {
                float e0 = __expf(p[t4 * 4 + rp * 2] - mnew);
                float e1 = __expf(p[t4 * 4 + rp * 2 + 1] - mnew);
                ls += e0 + e1;
                f16x2 pk; pk[0] = (_Float16)e0; pk[1] = (_Float16)e1;
                *(f16x2*)&Pw[SWZ(col, t4 * 16 + g * 4 + rp * 2)] = pk;
            }
        ls += __shfl_xor(ls, 16);
        ls += __shfl_xor(ls, 32);
        l_run = l_run * corr + ls;
        m_run = mnew;

        __builtin_amdgcn_wave_barrier();

        __syncthreads();                 // (A)
        if (pf) kwrite(kr);

        #pragma unroll
        for (int dt = 0; dt < 4; ++dt) {
            oacc[dt][0] *= corr; oacc[dt][1] *= corr;
            oacc[dt][2] *= corr; oacc[dt][3] *= corr;
        }
        #pragma unroll
        for (int c = 0; c < 2; ++c) {
            f16x8 pfv = *(const f16x8*)&Pw[SWZ(col, c * 32 + oct)];
            #pragma unroll
            for (int dt = 0; dt < 4; ++dt) {
                f16x8 vh = *(const f16x8*)&lds[8192 + SWZ(dt * 16 + col, c * 32 + oct)];
                oacc[dt] = mfma16(vh, pfv, oacc[dt]);
            }
        }

        __syncthreads();                 // (B)
        if (pf) vwrite(vA, vB);
    }

    if (isseg) {
        float* po = partO + (size_t)slot * 4096;
        #pragma unroll
        for (int dt = 0; dt < 4; ++dt)
            #pragma unroll
            for (int r = 0; r < 4; ++r)
                po[(dt * 16 + g * 4 + r) * 64 + w * 16 + col] = oacc[dt][r];
        if (g == 0) {
            partML[(size_t)slot * 128 + w * 16 + col] = m_run;
            partML[(size_t)slot * 128 + 64 + w * 16 + col] = l_run;
        }
        return;
    }

    {
        const float wt = __expf(-m_run);
        l_run += (float)(S_ - q0 - 64) * wt;
        const float* vs = vsufB + (size_t)(i + 1) * 64;
        #pragma unroll
        for (int dt = 0; dt < 4; ++dt)
            #pragma unroll
            for (int r = 0; r < 4; ++r)
                oacc[dt][r] += wt * vs[dt * 16 + g * 4 + r];
    }
    const float inv = 1.f / l_run;
    float* ow = (float*)&lds[w * 4096];
    const int q = lane >> 2, jj = lane & 3;
    #pragma unroll
    for (int half = 0; half < 2; ++half) {
        __builtin_amdgcn_wave_barrier();
        #pragma unroll
        for (int t4 = 0; t4 < 2; ++t4)
            #pragma unroll
            for (int r = 0; r < 4; ++r)
                ow[col * 40 + t4 * 16 + g * 4 + r] = oacc[half * 2 + t4][r] * inv;
        __builtin_amdgcn_wave_barrier();
        f32x4 v0 = *(const f32x4*)&ow[q * 40 + jj * 8];
        f32x4 v1 = *(const f32x4*)&ow[q * 40 + jj * 8 + 4];
        ushort8 hi = pack2x4h(v0, v1);
        const int m = brow + q0 + w * 16 + q;
        const int chunk = (half * 4 + jj) ^ (m & 7);
        *(ushort8*)&ohi[(size_t)m * 1024 + h * 64 + chunk * 8] = hi;
    }
}

// ---------------------------------------------------------------------------
// Combine partials for split q-tiles (i>=16), batched: grid (16, 32).
// ---------------------------------------------------------------------------
__global__ __launch_bounds__(256) void attn_combine_kernel(
    const float* __restrict__ partO, const float* __restrict__ partML,
    const float* __restrict__ vsuf,
    unsigned short* __restrict__ ohi)
{
    const int i = 16 + blockIdx.x;              // 16..31
    const int bh = blockIdx.y;
    const int b = bh >> 4, h = bh & 15;
    const float* vsufB = vsuf + (size_t)bh * 33 * 64;
    const int brow = b * 2048;
    const int nseg = 2;
    const int slot0 = (bh << 5) + (i - 16) * 2;
    const int q = threadIdx.x & 63, dgrp = threadIdx.x >> 6;
    const int q0 = i * 64;

    float mstar = 0.f;                          // masked logit 0 joins the max
    for (int sg = 0; sg < nseg; ++sg)
        mstar = fmaxf(mstar, partML[(size_t)(slot0 + sg) * 128 + q]);
    const float wtail = __expf(-mstar);
    float lstar = (float)(S_ - q0 - 64) * wtail;

    float od[16];
    const float* vs = vsufB + (size_t)(i + 1) * 64 + dgrp * 16;
    #pragma unroll
    for (int k = 0; k < 16; ++k) od[k] = wtail * vs[k];

    for (int sg = 0; sg < nseg; ++sg) {
        const float ms = partML[(size_t)(slot0 + sg) * 128 + q];
        const float lsv = partML[(size_t)(slot0 + sg) * 128 + 64 + q];
        const float wv = __expf(ms - mstar);
        lstar += lsv * wv;
        const float* po = partO + (size_t)(slot0 + sg) * 4096 + (size_t)(dgrp * 16) * 64 + q;
        #pragma unroll
        for (int k = 0; k < 16; ++k) od[k] += wv * po[k * 64];
    }

    const float inv = 1.f / lstar;
    f32x4 a0, a1, b0, b1;
    #pragma unroll
    for (int k = 0; k < 4; ++k) {
        a0[k] = od[k] * inv; a1[k] = od[4 + k] * inv;
        b0[k] = od[8 + k] * inv; b1[k] = od[12 + k] * inv;
    }
    ushort8 hi0 = pack2x4h(a0, a1);
    ushort8 hi1 = pack2x4h(b0, b1);
    const int mrow = brow + q0 + q;
    const int c0 = (dgrp * 2) ^ (mrow & 7);
    const int c1 = (dgrp * 2 + 1) ^ (mrow & 7);
    const size_t base = (size_t)mrow * 1024 + h * 64;
    *(ushort8*)&ohi[base + c0 * 8] = hi0;
    *(ushort8*)&ohi[base + c1 * 8] = hi1;
}

// ---------------------------------------------------------------------------
extern "C" void kernel_launch(void* const* d_in, const int* in_sizes, int n_in,
                              void* d_out, int out_size, void* d_ws, size_t ws_size,
                              hipStream_t stream) {
    const float* x     = (const float*)d_in[0];   // [B,S,D]
    const float* W_qkv = (const float*)d_in[1];   // [D,3D]
    const float* b_qkv = (const float*)d_in[2];   // [3D]
    const float* W_out = (const float*)d_in[3];   // [D,D]
    const float* b_out = (const float*)d_in[4];   // [D]
    float* out = (float*)d_out;                   // [B,S,D]

    // ws layout (~76.6 MB; ws >= 84.2 MB proven since r8 fused path)
    unsigned short* us  = (unsigned short*)d_ws;
    unsigned short* Wqh = us;                                  // [3072][1024]
    unsigned short* Wql = Wqh + (size_t)3072 * 1024;
    unsigned short* Woh = Wql + (size_t)3072 * 1024;           // [1024][1024]
    unsigned short* Wol = Woh + (size_t)1024 * 1024;
    unsigned short* XAhi = Wol + (size_t)1024 * 1024;          // [4096][1024] X, then attn-out (hi)
    unsigned short* QKVh = XAhi + (size_t)4096 * 1024;         // [4096][3072]
    unsigned short* QKVl = QKVh + (size_t)4096 * 3072;
    float* tsum   = (float*)(QKVl + (size_t)4096 * 3072);      // [32][32][64]
    float* vsuf   = tsum + (size_t)32 * 32 * 64;               // [32][33][64]
    float* partML = vsuf + (size_t)32 * 33 * 64;               // [1024][128]

    float* partO = out;                        // [1024][4096] = exactly d_out
    float* p1    = (float*)QKVh;               // split-K half-1 (dead after attn)

    conv_wt_kernel<<<dim3(16, 48), 256, 0, stream>>>(W_qkv, 3072, Wqh, Wql);
    conv_wt_kernel<<<dim3(16, 16), 256, 0, stream>>>(W_out, 1024, Woh, Wol);
    conv_rows_kernel<<<dim3(2048), 256, 0, stream>>>(x, XAhi);

    // fused-batch QKV projection: grid 768 = 3 blocks/CU
    gemm_pipe_kernel<1><<<dim3(24, 32), 256, 0, stream>>>(
        XAhi, Wqh, Wql, b_qkv, nullptr, nullptr, QKVh, QKVl, 4096, 3072, 1024);

    // batched V-suffix sums
    vsuf_part_kernel<<<dim3(32, 8), 256, 0, stream>>>(QKVh, QKVl, tsum);
    vsuf_scan_kernel<<<dim3(32), 64, 0, stream>>>(tsum, vsuf);

    // batch-fused attention + combine
    attn_kernel<<<dim3(48, 32), 256, 0, stream>>>(
        QKVh, QKVl, vsuf, XAhi, partO, partML);
    attn_combine_kernel<<<dim3(16, 32), 256, 0, stream>>>(
        partO, partML, vsuf, XAhi);

    // split-K output projection: one launch, both K-halves co-resident.
    // lower 32 y-blocks: K[0,512) + bias -> out; upper: K[512,1024) -> p1
    gemm_pipe_kernel<2><<<dim3(8, 64), 256, 0, stream>>>(
        XAhi, Woh, Wol, b_out, out, p1, nullptr, nullptr, 4096, 1024, 512);
    addp_kernel<<<dim3(4096), 256, 0, stream>>>(out, p1);
}